// Round 13
// baseline (568.861 us; speedup 1.0000x reference)
//
#include <hip/hip_runtime.h>

// ---------------- problem constants ----------------
constexpr int CB   = 8;      // batch
constexpr int CN   = 1369;   // tokens (37*37)
constexpr int CDIN = 768;
constexpr int CS   = 7;      // slots
constexpr int CD   = 256;
constexpr int CITERS = 3;
constexpr int CRES = 37;
constexpr float CSIGMA = 5.0f;
constexpr int CBS = CB * CS;        // 56
constexpr int CBN = CB * CN;        // 10952 rows for initial mlp
constexpr int CKV = 2 * CD;         // interleaved KX|VX row stride
constexpr float LNEPS = 1e-5f;
constexpr float ATTN_EPS = 1e-8f;

typedef unsigned short u16;
typedef short bs8 __attribute__((ext_vector_type(8)));   // 8 bf16 (bit pattern in shorts)
typedef float f4 __attribute__((ext_vector_type(4)));

// ---------------- helpers ----------------
__device__ __forceinline__ float ag_x(int n) { return -1.f + (float)(n % CRES) * (2.f / 36.f); }
__device__ __forceinline__ float ag_y(int n) { return -1.f + (float)(n / CRES) * (2.f / 36.f); }

__device__ __forceinline__ u16 bf_rne(float f) {
    unsigned u = __float_as_uint(f);
    return (u16)((u + 0x7FFFu + ((u >> 16) & 1u)) >> 16);
}
__device__ __forceinline__ float bf_to_f(u16 h) { return __uint_as_float(((unsigned)h) << 16); }

__device__ __forceinline__ void split2b(float v, u16& h, u16& m) {
    h = bf_rne(v);
    m = bf_rne(v - bf_to_f(h));
}

// async global->LDS, 16B per lane (dest = wave-uniform base + lane*16)
__device__ __forceinline__ void async16(const u16* g, u16* l) {
    __builtin_amdgcn_global_load_lds(
        (const __attribute__((address_space(1))) unsigned int*)g,
        (__attribute__((address_space(3))) unsigned int*)l, 16, 0, 0);
}

// 256-thread block sum
__device__ __forceinline__ float block_reduce_sum(float v, float* sbuf) {
    #pragma unroll
    for (int off = 32; off > 0; off >>= 1) v += __shfl_down(v, off, 64);
    if ((threadIdx.x & 63) == 0) sbuf[threadIdx.x >> 6] = v;
    __syncthreads();
    if (threadIdx.x == 0) sbuf[0] = sbuf[0] + sbuf[1] + sbuf[2] + sbuf[3];
    __syncthreads();
    float r = sbuf[0];
    __syncthreads();
    return r;
}

// 128-thread block sum (2 waves)
__device__ __forceinline__ float block_reduce_sum128(float v, float* sbuf) {
    #pragma unroll
    for (int off = 32; off > 0; off >>= 1) v += __shfl_down(v, off, 64);
    if ((threadIdx.x & 63) == 0) sbuf[threadIdx.x >> 6] = v;
    __syncthreads();
    float r = sbuf[0] + sbuf[1];
    __syncthreads();
    return r;
}

// ---------------- LN of (xa+xb+bias) -> split-2 bf16 planes (d=256) ----------------
// Used after split-K hgemm#2: xD = xa + xb (K-halves) + im_b2.
__global__ __launch_bounds__(256) void ln_planes_sum2_kernel(
        const float* __restrict__ xa, const float* __restrict__ xb,
        const float* __restrict__ bias,
        u16* __restrict__ Yh, u16* __restrict__ Ym,
        const float* __restrict__ g, const float* __restrict__ b) {
    __shared__ float sbuf[8];
    int row = blockIdx.x, t = threadIdx.x;
    size_t idx = (size_t)row * CD + t;
    float v0 = xa[idx] + xb[idx] + bias[t];
    float mean = block_reduce_sum(v0, sbuf) / CD;
    float d0 = v0 - mean;
    float var = block_reduce_sum(d0 * d0, sbuf) / CD;
    float rstd = rsqrtf(var + LNEPS);
    float y = d0 * rstd * g[t] + b[t];
    u16 h, m; split2b(y, h, m);
    Yh[idx] = h; Ym[idx] = m;
}

// ---------------- mega prep: ln_planes(inputs,768) + transposes + wprep + accZero ----------------
// bid [0, CBN): LN row -> xln planes
// bid [CBN, CBN+576): transpose im_w1 tile; [CBN+576, CBN+768): im_w2 tile
// bid [CBN+768, CBN+768+1541): wprep block (kv planes / Pq / Pg / g2 / bg / wqb)
// bid [CBN+2309, CBN+2309+29): zero accumulators (Wacc|msumA|msumB|slotsAcc)
__global__ __launch_bounds__(256) void mega_prep_kernel(
        const float* __restrict__ inputs, u16* __restrict__ xlnh, u16* __restrict__ xlnm,
        const float* __restrict__ im_ln1_g, const float* __restrict__ im_ln1_b,
        const float* __restrict__ im_w1, u16* __restrict__ w1th, u16* __restrict__ w1tm,
        const float* __restrict__ im_w2, u16* __restrict__ w2th, u16* __restrict__ w2tm,
        const float* __restrict__ Wk, const float* __restrict__ Wv,
        const float* __restrict__ Wq,
        const float* __restrict__ f_w1, const float* __restrict__ f_w2,
        u16* __restrict__ kvth, u16* __restrict__ kvtm, float* __restrict__ Pq,
        const float* __restrict__ wih, float* __restrict__ Pg,
        const float* __restrict__ g_w, const float* __restrict__ g_b,
        const float* __restrict__ f_b1,
        float* __restrict__ G2, float* __restrict__ gb1,
        const float* __restrict__ f_b2, const float* __restrict__ bih,
        float* __restrict__ bg, float* __restrict__ wqb,
        float* __restrict__ accZ, int accN) {
    __shared__ float shm[1056];        // union: sbuf[8] | tile[32][33] | arow[256]
    int bid = blockIdx.x;
    int t = threadIdx.x;
    if (bid < CBN) {
        // ---- ln_planes d=768 ----
        int row = bid;
        const float* x = inputs + (size_t)row * CDIN;
        float v0 = x[t], v1 = x[t + 256], v2 = x[t + 512];
        float mean = block_reduce_sum(v0 + v1 + v2, shm) / CDIN;
        float d0 = v0 - mean, d1 = v1 - mean, d2 = v2 - mean;
        float var = block_reduce_sum(d0 * d0 + d1 * d1 + d2 * d2, shm) / CDIN;
        float rstd = rsqrtf(var + LNEPS);
        u16 h, m;
        float y = d0 * rstd * im_ln1_g[t] + im_ln1_b[t];
        split2b(y, h, m);
        xlnh[(size_t)row * CDIN + t] = h; xlnm[(size_t)row * CDIN + t] = m;
        float y1 = d1 * rstd * im_ln1_g[t + 256] + im_ln1_b[t + 256];
        split2b(y1, h, m);
        xlnh[(size_t)row * CDIN + t + 256] = h; xlnm[(size_t)row * CDIN + t + 256] = m;
        float y2 = d2 * rstd * im_ln1_g[t + 512] + im_ln1_b[t + 512];
        split2b(y2, h, m);
        xlnh[(size_t)row * CDIN + t + 512] = h; xlnm[(size_t)row * CDIN + t + 512] = m;
        return;
    }
    if (bid < CBN + 768) {
        // ---- transpose_split2 ----
        int tb = bid - CBN;
        const float* W; u16 *Th, *Tm; int N, bx, by;
        if (tb < 576) { W = im_w1; Th = w1th; Tm = w1tm; N = CDIN; bx = tb % 24; by = tb / 24; }
        else { tb -= 576; W = im_w2; Th = w2th; Tm = w2tm; N = CD; bx = tb % 8; by = tb / 8; }
        int K = CDIN;
        float (*tile)[33] = (float(*)[33])shm;
        int nb = bx * 32, kb = by * 32;
        int tx = t & 31, ty = t >> 5;
        #pragma unroll
        for (int i = 0; i < 32; i += 8)
            tile[ty + i][tx] = W[(size_t)(kb + ty + i) * N + nb + tx];
        __syncthreads();
        #pragma unroll
        for (int i = 0; i < 32; i += 8) {
            float v = tile[tx][ty + i];
            u16 h, m; split2b(v, h, m);
            size_t idx = (size_t)(nb + ty + i) * K + kb + tx;
            Th[idx] = h; Tm[idx] = m;
        }
        return;
    }
    if (bid >= CBN + 768 + 1541) {
        // ---- zero accumulators ----
        int zb = bid - (CBN + 768 + 1541);
        int fi = (zb * 256 + t) * 4;
        if (fi + 3 < accN) *(f4*)(accZ + fi) = (f4){0.f, 0.f, 0.f, 0.f};
        else for (int i = fi; i < accN; i++) accZ[i] = 0.f;
        return;
    }
    // ---- wprep ----
    int wb = bid - CBN - 768;
    float* arow = shm;
    int n = t;
    if (wb < 512) {
        const float* A = (wb < 256) ? Wk : Wv;
        int k = wb & 255;
        size_t poff = (wb < 256) ? 0 : (size_t)CD * CD;
        arow[n] = A[k * CD + n];
        __syncthreads();
        float acc = 0.f;
        for (int j = 0; j < CD; j++) acc += arow[j] * f_w1[(size_t)j * CD + n];
        u16 h, m; split2b(acc, h, m);
        kvth[poff + (size_t)n * CD + k] = h;
        kvtm[poff + (size_t)n * CD + k] = m;
    } else if (wb < 768) {
        int k = wb - 512;
        arow[n] = Wq[k * CD + n];
        __syncthreads();
        float acc = 0.f;
        for (int c = 0; c < CD; c++) acc += arow[c] * f_w2[(size_t)n * CD + c];
        Pq[(size_t)k * CD + n] = acc;
    } else if (wb < 1536) {
        int wb2 = wb - 768;
        int k = wb2 & 255;
        int ny = wb2 >> 8;
        arow[n] = f_w2[k * CD + n];
        __syncthreads();
        int nn = ny * 256 + n;
        float acc = 0.f;
        for (int j = 0; j < CD; j++) acc += arow[j] * wih[(size_t)j * (3 * CD) + nn];
        Pg[(size_t)k * (3 * CD) + nn] = acc;
    } else if (wb == 1536) {
        float a0 = 0.f, a1 = 0.f, ab = 0.f;
        for (int j = 0; j < CD; j++) {
            float w = f_w1[j * CD + n];
            a0 += g_w[j] * w;
            a1 += g_w[CD + j] * w;
            ab += g_b[j] * w;
        }
        G2[n] = a0; G2[CD + n] = a1; gb1[n] = ab + f_b1[n];
    } else if (wb <= 1539) {
        int nn = (wb - 1537) * 256 + n;
        float s = bih[nn];
        for (int c = 0; c < CD; c++) s += f_b2[c] * wih[(size_t)c * (3 * CD) + nn];
        bg[nn] = s;
    } else {
        float s = 0.f;
        for (int c = 0; c < CD; c++) s += Wq[n * CD + c] * f_b2[c];
        wqb[n] = s;
    }
}

// ---------------- bf16x3 plane GEMM, BM=64 x BN, NBUF-deep counted-vmcnt pipeline ----------------
// Supports split-K via gridDim.z: z-slice kz covers K/gridDim.z contiguous k,
// writing Cf (kz=0) or Cf2 (kz=1). Caller sums the halves (bias applied there).
// #1: BN=128, NBUF=2, z=1 (proven ~69us). #2: BN=64, NBUF=3, z=2 (coverage 5.4/CU,
// 12 k-steps). #3: BN=128, NBUF=2, z=1.
// LDS slot swizzle via inverse-permuted global source; bijective XCD swizzle.
// NOTE: SQ_LDS_BANK_CONFLICT ~= 8 cyc per global_load_lds wave-issue is the
// structural LDS-write transfer time (1024B / 128B-per-cyc), not fixable.
template<int BN, int NBUF>
__global__ __launch_bounds__(256)
void hgemm2(const u16* __restrict__ Ah, const u16* __restrict__ Am,
            const u16* __restrict__ Bh, const u16* __restrict__ Bm,
            int M, int N, int K, const float* __restrict__ bias, int relu,
            float* __restrict__ Cf, u16* __restrict__ Ch, u16* __restrict__ Cm,
            float* __restrict__ Cf2) {
    constexpr int BP = BN * 32;            // u16 per B plane
    constexpr int SB = 4096 + 2 * BP;      // u16 per LDS buffer
    constexpr int NI = 2 + 2 * (BN / 64);  // staging issues per k-step: 6 or 4
    constexpr int NF = BN / 32;            // B frags per wave: 4 or 2
    constexpr int PP = BN / 64;            // issues per B plane: 2 or 1
    __shared__ u16 smem[NBUF][SB];
    const int tid = threadIdx.x;

    int bx = blockIdx.x, by = blockIdx.y;
    {
        int gx = gridDim.x;
        int nwg = gx * gridDim.y;
        if (!(nwg & 7)) {               // XCD-aware swizzle (bijective, nwg%8==0)
            int bid = by * gx + bx;
            int cpx = nwg >> 3;
            int s = (bid & 7) * cpx + (bid >> 3);
            bx = s % gx; by = s / gx;
        }
    }
    const int Keff = K / (int)gridDim.z;
    const int koff = (int)blockIdx.z * Keff;
    float* Cout = (blockIdx.z == 0) ? Cf : Cf2;
    const int m0 = by * 64, n0 = bx * BN;
    const int w = tid >> 6, lane = tid & 63;
    const int wm = w & 1, wn = w >> 1;
    const int l15 = lane & 15, l4 = lane >> 4;

    // staging map: i0=Ah, i1=Am, then B planes (PP issues each)
    const u16* srcp[NI];
    int dsto[NI];
    #pragma unroll
    for (int i = 0; i < NI; i++) {
        const u16* bp; int row, r, c;
        if (i < 2) {                       // A planes: 64 rows x 4 chunks = 256
            int qq = tid;
            r = qq >> 2;
            c = (qq & 3) ^ ((r ^ (r >> 2)) & 3);   // inverse swizzle on source
            bp = (i == 0) ? Ah : Am;
            row = m0 + r; row = row < M ? row : M - 1;
            dsto[i] = i * 2048 + w * 512;
        } else {                           // B planes: BN rows x 4 chunks
            int ii = i - 2;
            int plane = ii / PP;           // 0:Bh 1:Bm
            int sub = ii % PP;
            int qq = sub * 256 + tid;
            r = qq >> 2;
            c = (qq & 3) ^ ((r ^ (r >> 2)) & 3);
            bp = plane ? Bm : Bh;
            row = n0 + r;
            dsto[i] = 4096 + plane * BP + sub * 2048 + w * 512;
        }
        srcp[i] = bp + (size_t)row * K + koff + c * 8;
    }

    f4 acc[2][NF];
    #pragma unroll
    for (int i = 0; i < 2; i++)
        #pragma unroll
        for (int j = 0; j < NF; j++) acc[i][j] = (f4){0.f, 0.f, 0.f, 0.f};

    // swizzled k-chunk slot for fragment reads
    const int cx8 = (l4 ^ (l15 & 3) ^ ((l15 >> 2) & 3)) * 8;

    const int ns = Keff / 32;
    // prologue: stage steps 0..D-1 (no drain)
    #pragma unroll
    for (int d = 0; d < NBUF - 1; d++)
        #pragma unroll
        for (int i = 0; i < NI; i++) async16(srcp[i] + d * 32, &smem[d][dsto[i]]);

    u16* c0 = &smem[0][0];
    u16* c1 = &smem[NBUF > 1 ? 1 : 0][0];
    u16* c2 = &smem[NBUF - 1][0];

    for (int k = 0; k < ns; k++) {
        if constexpr (NBUF == 3) {
            if (k + 2 < ns) {
                #pragma unroll
                for (int i = 0; i < NI; i++) async16(srcp[i] + (k + 2) * 32, c2 + dsto[i]);
                if constexpr (BN == 64) asm volatile("s_waitcnt vmcnt(8)" ::: "memory");
                else                     asm volatile("s_waitcnt vmcnt(12)" ::: "memory");
            } else if (k + 1 < ns) {
                if constexpr (BN == 64) asm volatile("s_waitcnt vmcnt(4)" ::: "memory");
                else                     asm volatile("s_waitcnt vmcnt(6)" ::: "memory");
            } else {
                asm volatile("s_waitcnt vmcnt(0)" ::: "memory");
            }
        } else {
            if (k + 1 < ns) {
                #pragma unroll
                for (int i = 0; i < NI; i++) async16(srcp[i] + (k + 1) * 32, c1 + dsto[i]);
                if constexpr (BN == 64) asm volatile("s_waitcnt vmcnt(4)" ::: "memory");
                else                     asm volatile("s_waitcnt vmcnt(6)" ::: "memory");
            } else {
                asm volatile("s_waitcnt vmcnt(0)" ::: "memory");
            }
        }
        __builtin_amdgcn_s_barrier();        // all threads' step-k loads landed
        bs8 ah[2], am[2], bh[NF], bm[NF];
        #pragma unroll
        for (int f = 0; f < 2; f++) {
            int oa = (wm * 32 + f * 16 + l15) * 32 + cx8;
            ah[f] = *(const bs8*)(c0 + oa);
            am[f] = *(const bs8*)(c0 + 2048 + oa);
        }
        #pragma unroll
        for (int f = 0; f < NF; f++) {
            int ob = (wn * (NF * 16) + f * 16 + l15) * 32 + cx8;
            bh[f] = *(const bs8*)(c0 + 4096 + ob);
            bm[f] = *(const bs8*)(c0 + 4096 + BP + ob);
        }
        #pragma unroll
        for (int mf = 0; mf < 2; mf++)
            #pragma unroll
            for (int nf = 0; nf < NF; nf++) {
                acc[mf][nf] = __builtin_amdgcn_mfma_f32_16x16x32_bf16(am[mf], bh[nf], acc[mf][nf], 0, 0, 0);
                acc[mf][nf] = __builtin_amdgcn_mfma_f32_16x16x32_bf16(ah[mf], bm[nf], acc[mf][nf], 0, 0, 0);
                acc[mf][nf] = __builtin_amdgcn_mfma_f32_16x16x32_bf16(ah[mf], bh[nf], acc[mf][nf], 0, 0, 0);
            }
        asm volatile("" ::: "memory");       // keep LDS reads ordered vs barrier
        __builtin_amdgcn_s_barrier();        // all done reading c0 (no vmcnt drain!)
        if constexpr (NBUF == 3) { u16* t_ = c0; c0 = c1; c1 = c2; c2 = t_; }
        else                     { u16* t_ = c0; c0 = c1; c1 = t_; }
    }

    #pragma unroll
    for (int mf = 0; mf < 2; mf++)
        #pragma unroll
        for (int i = 0; i < 4; i++) {
            int grow = m0 + wm * 32 + mf * 16 + l4 * 4 + i;
            if (grow < M) {
                #pragma unroll
                for (int nf = 0; nf < NF; nf++) {
                    int col = n0 + wn * (NF * 16) + nf * 16 + l15;
                    float v = acc[mf][nf][i] + (bias ? bias[col] : 0.f);
                    if (relu) v = fmaxf(v, 0.f);
                    if (Cout) Cout[(size_t)grow * N + col] = v;
                    else {
                        u16 h, m; split2b(v, h, m);
                        Ch[(size_t)grow * N + col] = h;
                        Cm[(size_t)grow * N + col] = m;
                    }
                }
            }
        }
}

// gi/gh pair in one launch via blockIdx.z; z==0 rows scaled by 1/m0 (from msum)
__global__ __launch_bounds__(128) void rowgemmG_kernel(
        const float* __restrict__ A0, const float* __restrict__ W0,
        const float* __restrict__ b0, float* __restrict__ C0,
        const float* __restrict__ A1, const float* __restrict__ W1,
        const float* __restrict__ b1, float* __restrict__ C1,
        const float* __restrict__ msum, int N, int K) {
    __shared__ float sA[256];
    const float* A = blockIdx.z ? A1 : A0;
    const float* W = blockIdx.z ? W1 : W0;
    const float* B = blockIdx.z ? b1 : b0;
    float* C = blockIdx.z ? C1 : C0;
    int r = blockIdx.x;
    int c = blockIdx.y * 128 + threadIdx.x;
    float scl = blockIdx.z ? 1.f : 1.f / msum[r * 8];
    for (int i = threadIdx.x; i < K; i += 128) sA[i] = A[(size_t)r * K + i] * scl;
    __syncthreads();
    float a0 = 0.f, a1 = 0.f, a2 = 0.f, a3 = 0.f;
    #pragma unroll 4
    for (int k = 0; k < K; k += 4) {
        a0 += sA[k]     * W[(size_t)k * N + c];
        a1 += sA[k + 1] * W[(size_t)(k + 1) * N + c];
        a2 += sA[k + 2] * W[(size_t)(k + 2) * N + c];
        a3 += sA[k + 3] * W[(size_t)(k + 3) * N + c];
    }
    C[(size_t)r * N + c] = (a0 + a1) + (a2 + a3) + B[c];
}

// ---------------- fused init: slots broadcast + S init + LN + qb0 + qw (t=0) ----------------
__global__ __launch_bounds__(256) void init_ln_q_kernel(const float* __restrict__ slots_init_p,
        const float* __restrict__ S_s0, const float* __restrict__ S_p0,
        const float* __restrict__ ln_g, const float* __restrict__ ln_b,
        const float* __restrict__ wqb, const float* __restrict__ Pq,
        float* __restrict__ slots, float* __restrict__ S_s, float* __restrict__ S_p,
        float* __restrict__ qwb, float* __restrict__ qb0) {
    __shared__ float sbuf[8];
    __shared__ float sN[CD];
    int row = blockIdx.x, t = threadIdx.x;
    int s = row % CS;
    float x = slots_init_p[s * CD + t];
    slots[row * CD + t] = x;
    if (t < 2) { S_s[row * 2 + t] = S_s0[s * 2 + t]; S_p[row * 2 + t] = S_p0[s * 2 + t]; }
    float mean = block_reduce_sum(x, sbuf) / CD;
    float d0 = x - mean;
    float var = block_reduce_sum(d0 * d0, sbuf) / CD;
    float sn = d0 * rsqrtf(var + LNEPS) * ln_g[t] + ln_b[t];
    sN[t] = sn;
    float qb = block_reduce_sum(sn * wqb[t], sbuf);
    if (t == 0) qb0[row] = qb;
    __syncthreads();
    float acc = 0.f;
    #pragma unroll 4
    for (int k = 0; k < CD; k++) acc += sN[k] * Pq[(size_t)k * CD + t];
    qwb[row * CD + t] = acc;
}

// fused slots finalize: slots = snew + b2 + slotsAcc (w2 GEMV pre-accumulated by
// gate_mlp1 via atomics); zero slotsAcc for next iter; LN + qb0 + qw GEMV.
__global__ __launch_bounds__(256) void slotsup_kernel(float* __restrict__ slotsAcc,
        const float* __restrict__ b2, const float* __restrict__ snewb,
        const float* __restrict__ ln_g, const float* __restrict__ ln_b,
        const float* __restrict__ wqb, const float* __restrict__ Pq,
        float* __restrict__ slots, float* __restrict__ qwb, float* __restrict__ qb0) {
    __shared__ float sbuf[8];
    __shared__ float sN[CD];
    int row = blockIdx.x, t = threadIdx.x;
    float v = snewb[row * CD + t] + b2[t] + slotsAcc[row * CD + t];
    slotsAcc[row * CD + t] = 0.f;          // ready for next iteration's atomics
    slots[row * CD + t] = v;
    float mean = block_reduce_sum(v, sbuf) / CD;
    float d0 = v - mean;
    float var = block_reduce_sum(d0 * d0, sbuf) / CD;
    float sn = d0 * rsqrtf(var + LNEPS) * ln_g[t] + ln_b[t];
    sN[t] = sn;
    float qb = block_reduce_sum(sn * wqb[t], sbuf);
    if (t == 0) qb0[row] = qb;
    __syncthreads();
    float acc = 0.f;
    #pragma unroll 4
    for (int k = 0; k < CD; k++) acc += sN[k] * Pq[(size_t)k * CD + t];
    qwb[row * CD + t] = acc;
}

// dots + softmax-over-slots + (optional) vsum + (optional) fused moments.
// Moments are lane-distributed: lanes 0-34 each own one (slot, moment) pair.
__global__ __launch_bounds__(256) void dotsv_kernel(const float* __restrict__ KVX,
        const float* __restrict__ S_p, const float* __restrict__ S_s,
        const float* __restrict__ msum_in, int useMsum,
        const float* __restrict__ G2, const float* __restrict__ gb1,
        const float* __restrict__ qw, const float* __restrict__ qb0,
        float* __restrict__ attn, float* __restrict__ Wacc,
        float* __restrict__ msum_out) {
    __shared__ float sred[4 * CD];
    int b = blockIdx.x;
    int w = threadIdx.x >> 6, l = threadIdx.x & 63;
    int k4 = l * 4;
    float4 g0 = *(const float4*)(G2 + k4);
    float4 g1 = *(const float4*)(G2 + CD + k4);
    float4 gb = *(const float4*)(gb1 + k4);
    float4 qwv[CS]; float px[CS], py[CS], ix[CS], iy[CS], q0[CS];
    #pragma unroll
    for (int s = 0; s < CS; s++) {
        int bs = b * CS + s;
        qwv[s] = *(const float4*)(qw + bs * CD + k4);
        if (useMsum) {
            const float* mp = msum_in + bs * 8;
            float m0 = mp[0];
            float pxv = mp[1] / m0, pyv = mp[2] / m0;
            float sx = sqrtf(fmaxf(mp[3] / m0 - pxv * pxv, 0.f));
            float sy = sqrtf(fmaxf(mp[4] / m0 - pyv * pyv, 0.f));
            px[s] = pxv; py[s] = pyv;
            ix[s] = 1.f / (sx * CSIGMA); iy[s] = 1.f / (sy * CSIGMA);
        } else {
            px[s] = S_p[2 * bs]; py[s] = S_p[2 * bs + 1];
            ix[s] = 1.f / (S_s[2 * bs] * CSIGMA); iy[s] = 1.f / (S_s[2 * bs + 1] * CSIGMA);
        }
        q0[s] = qb0[bs];
    }
    float4 acc[CS];
    #pragma unroll
    for (int s = 0; s < CS; s++) acc[s] = make_float4(0.f, 0.f, 0.f, 0.f);
    float wmv = 0.f;
    int sidx = l / 5;
    int jidx = l - sidx * 5;
    int nbase = blockIdx.y * 16 + w * 4;
    #pragma unroll
    for (int i = 0; i < 4; i++) {
        int n = nbase + i;
        int nc = n < CN ? n : CN - 1;
        const float* rowp = KVX + (size_t)(b * CN + nc) * CKV;
        float4 kx = *(const float4*)(rowp + k4);
        float ax = ag_x(nc), ay = ag_y(nc);
        float dsv[CS];
        #pragma unroll
        for (int s = 0; s < CS; s++) {
            float r0 = (ax - px[s]) * ix[s];
            float r1 = (ay - py[s]) * iy[s];
            float v0 = fmaxf(kx.x + r0 * g0.x + r1 * g1.x + gb.x, 0.f);
            float v1 = fmaxf(kx.y + r0 * g0.y + r1 * g1.y + gb.y, 0.f);
            float v2 = fmaxf(kx.z + r0 * g0.z + r1 * g1.z + gb.z, 0.f);
            float v3 = fmaxf(kx.w + r0 * g0.w + r1 * g1.w + gb.w, 0.f);
            float d = v0 * qwv[s].x + v1 * qwv[s].y + v2 * qwv[s].z + v3 * qwv[s].w;
            #pragma unroll
            for (int off = 32; off > 0; off >>= 1) d += __shfl_xor(d, off, 64);
            dsv[s] = 0.0625f * (d + q0[s]);
        }
        float mx = -1e30f;
        #pragma unroll
        for (int s = 0; s < CS; s++) mx = fmaxf(mx, dsv[s]);
        float sum = 0.f;
        #pragma unroll
        for (int s = 0; s < CS; s++) { dsv[s] = __expf(dsv[s] - mx); sum += dsv[s]; }
        float inv = 1.f / sum;
        #pragma unroll
        for (int s = 0; s < CS; s++) dsv[s] = dsv[s] * inv + ATTN_EPS;
        if (attn && l == 0 && n < CN) {
            #pragma unroll
            for (int s = 0; s < CS; s++)
                attn[(size_t)(b * CS + s) * CN + n] = dsv[s];
        }
        if (msum_out && n < CN) {
            float ax2 = ax * ax, ay2 = ay * ay;
            float a = dsv[0];
            a = (sidx == 1) ? dsv[1] : a;
            a = (sidx == 2) ? dsv[2] : a;
            a = (sidx == 3) ? dsv[3] : a;
            a = (sidx == 4) ? dsv[4] : a;
            a = (sidx == 5) ? dsv[5] : a;
            a = (sidx == 6) ? dsv[6] : a;
            float coef = 1.f;
            coef = (jidx == 1) ? ax : coef;
            coef = (jidx == 2) ? ay : coef;
            coef = (jidx == 3) ? ax2 : coef;
            coef = (jidx == 4) ? ay2 : coef;
            wmv += a * coef;
        }
        if (Wacc && n < CN) {
            float4 vx = *(const float4*)(rowp + CD + k4);
            #pragma unroll
            for (int s = 0; s < CS; s++) {
                float r0 = (ax - px[s]) * ix[s];
                float r1 = (ay - py[s]) * iy[s];
                float a = dsv[s];
                acc[s].x += a * fmaxf(vx.x + r0 * g0.x + r1 * g1.x + gb.x, 0.f);
                acc[s].y += a * fmaxf(vx.y + r0 * g0.y + r1 * g1.y + gb.y, 0.f);
                acc[s].z += a * fmaxf(vx.z + r0 * g0.z + r1 * g1.z + gb.z, 0.f);
                acc[s].w += a * fmaxf(vx.w + r0 * g0.w + r1 * g1.w + gb.w, 0.f);
            }
        }
    }
    if (Wacc) {
        for (int s = 0; s < CS; s++) {
            ((float4*)sred)[w * 64 + l] = acc[s];
            __syncthreads();
            if (threadIdx.x < CD) {
                float v = sred[threadIdx.x] + sred[CD + threadIdx.x]
                        + sred[2 * CD + threadIdx.x] + sred[3 * CD + threadIdx.x];
                atomicAdd(&Wacc[(size_t)(b * CS + s) * CD + threadIdx.x], v);
            }
            __syncthreads();
        }
    }
    if (msum_out) {
        if (l < 35) sred[w * 35 + l] = wmv;
        __syncthreads();
        if (threadIdx.x < 35) {
            float v = sred[threadIdx.x] + sred[35 + threadIdx.x]
                    + sred[70 + threadIdx.x] + sred[105 + threadIdx.x];
            int s = threadIdx.x / 5, j = threadIdx.x % 5;
            atomicAdd(&msum_out[(size_t)(b * CS + s) * 8 + j], v);
        }
    }
}

// fused GRU gate + LN + h1 GEMV + partial slots GEMV (h1 @ w2 accumulated into
// slotsAcc via atomics). Grid (CBS, 8) x 128 threads; h1 never hits memory.
__global__ __launch_bounds__(128) void gate_mlp1_kernel(const float* __restrict__ giRaw,
        const float* __restrict__ ghRaw, const float* __restrict__ slots,
        const float* __restrict__ mg, const float* __restrict__ mb,
        const float* __restrict__ mlp_w1, const float* __restrict__ mlp_b1,
        const float* __restrict__ w2,
        float* __restrict__ snewb, float* __restrict__ slotsAcc,
        float* __restrict__ WaccZ, float* __restrict__ msumZ) {
    __shared__ float sbuf[4];
    __shared__ float sM[CD];
    __shared__ float sH1[128];
    int row = blockIdx.x, t = threadIdx.x;
    float snew[2];
    #pragma unroll
    for (int e = 0; e < 2; e++) {
        int tt = t + e * 128;
        float gi0 = giRaw[row * 3 * CD + tt];
        float gi1 = giRaw[row * 3 * CD + CD + tt];
        float gi2 = giRaw[row * 3 * CD + 2 * CD + tt];
        float gh0 = ghRaw[row * 3 * CD + tt];
        float gh1 = ghRaw[row * 3 * CD + CD + tt];
        float gh2 = ghRaw[row * 3 * CD + 2 * CD + tt];
        float r = 1.f / (1.f + expf(-(gi0 + gh0)));
        float z = 1.f / (1.f + expf(-(gi1 + gh1)));
        float nn = tanhf(gi2 + r * gh2);
        snew[e] = (1.f - z) * nn + z * slots[row * CD + tt];
    }
    if (blockIdx.y == 0) {
        snewb[row * CD + t] = snew[0];
        snewb[row * CD + t + 128] = snew[1];
        WaccZ[row * CD + t] = 0.f;
        WaccZ[row * CD + t + 128] = 0.f;
        if (t < 8) msumZ[row * 8 + t] = 0.f;
    }
    float mean = block_reduce_sum128(snew[0] + snew[1], sbuf) / CD;
    float d0 = snew[0] - mean, d1 = snew[1] - mean;
    float var = block_reduce_sum128(d0 * d0 + d1 * d1, sbuf) / CD;
    float rstd = rsqrtf(var + LNEPS);
    sM[t]       = d0 * rstd * mg[t] + mb[t];
    sM[t + 128] = d1 * rstd * mg[t + 128] + mb[t + 128];
    __syncthreads();
    int c = blockIdx.y * 128 + t;
    float a0 = 0.f, a1 = 0.f, a2 = 0.f, a3 = 0.f;
    #pragma unroll 4
    for (int k = 0; k < CD; k += 4) {
        a0 += sM[k]     * mlp_w1[(size_t)k * (4 * CD) + c];
        a1 += sM[k + 1] * mlp_w1[(size_t)(k + 1) * (4 * CD) + c];
        a2 += sM[k + 2] * mlp_w1[(size_t)(k + 2) * (4 * CD) + c];
        a3 += sM[k + 3] * mlp_w1[(size_t)(k + 3) * (4 * CD) + c];
    }
    sH1[t] = fmaxf((a0 + a1) + (a2 + a3) + mlp_b1[c], 0.f);
    __syncthreads();
    // partial slots GEMV over this block's 128 h1 values (k = by*128 + cc)
    float p0 = 0.f, p1 = 0.f;
    const float* w2b = w2 + (size_t)blockIdx.y * 128 * CD;
    #pragma unroll 4
    for (int cc = 0; cc < 128; cc++) {
        float h = sH1[cc];
        p0 += h * w2b[(size_t)cc * CD + t];
        p1 += h * w2b[(size_t)cc * CD + t + 128];
    }
    atomicAdd(&slotsAcc[row * CD + t], p0);
    atomicAdd(&slotsAcc[row * CD + t + 128], p1);
}

// fused final: by<2 -> out0 = slots @ fin_w + fin_b (128 cols each);
// by==2 -> attn row scale by 1/m0.
__global__ __launch_bounds__(128) void final_kernel(const float* __restrict__ slots,
        const float* __restrict__ fin_w, const float* __restrict__ fin_b,
        float* __restrict__ out0, float* __restrict__ attn,
        const float* __restrict__ msum) {
    int row = blockIdx.x;
    if (blockIdx.y == 2) {
        float inv = 1.f / msum[(size_t)row * 8];
        float* up = attn + (size_t)row * CN;
        for (int n = threadIdx.x; n < CN; n += 128) up[n] *= inv;
        return;
    }
    __shared__ float sA[CD];
    for (int i = threadIdx.x; i < CD; i += 128) sA[i] = slots[(size_t)row * CD + i];
    __syncthreads();
    int c = blockIdx.y * 128 + threadIdx.x;
    float a0 = 0.f, a1 = 0.f, a2 = 0.f, a3 = 0.f;
    #pragma unroll 4
    for (int k = 0; k < CD; k += 4) {
        a0 += sA[k]     * fin_w[(size_t)k * CD + c];
        a1 += sA[k + 1] * fin_w[(size_t)(k + 1) * CD + c];
        a2 += sA[k + 2] * fin_w[(size_t)(k + 2) * CD + c];
        a3 += sA[k + 3] * fin_w[(size_t)(k + 3) * CD + c];
    }
    out0[(size_t)row * CD + c] = (a0 + a1) + (a2 + a3) + fin_b[c];
}

// ---------------- launcher ----------------
extern "C" void kernel_launch(void* const* d_in, const int* in_sizes, int n_in,
                              void* d_out, int out_size, void* d_ws, size_t ws_size,
                              hipStream_t stream) {
    (void)in_sizes; (void)n_in; (void)out_size;
    const float* inputs       = (const float*)d_in[0];
    const float* slots_init_p = (const float*)d_in[1];
    const float* S_s0         = (const float*)d_in[2];
    const float* S_p0         = (const float*)d_in[3];
    const float* im_ln1_g = (const float*)d_in[4];
    const float* im_ln1_b = (const float*)d_in[5];
    const float* im_w1    = (const float*)d_in[6];
    const float* im_b1    = (const float*)d_in[7];
    const float* im_w2    = (const float*)d_in[8];
    const float* im_b2    = (const float*)d_in[9];
    const float* im_ln2_g = (const float*)d_in[10];
    const float* im_ln2_b = (const float*)d_in[11];
    const float* Wq  = (const float*)d_in[12];
    const float* Wk  = (const float*)d_in[13];
    const float* Wv  = (const float*)d_in[14];
    const float* g_w = (const float*)d_in[15];
    const float* g_b = (const float*)d_in[16];
    const float* f_w1 = (const float*)d_in[17];
    const float* f_b1 = (const float*)d_in[18];
    const float* f_w2 = (const float*)d_in[19];
    const float* f_b2 = (const float*)d_in[20];
    const float* ln_g = (const float*)d_in[21];
    const float* ln_b = (const float*)d_in[22];
    const float* gru_wih = (const float*)d_in[23];
    const float* gru_whh = (const float*)d_in[24];
    const float* gru_bih = (const float*)d_in[25];
    const float* gru_bhh = (const float*)d_in[26];
    const float* mlp_ln_g = (const float*)d_in[27];
    const float* mlp_ln_b = (const float*)d_in[28];
    const float* mlp_w1 = (const float*)d_in[29];
    const float* mlp_b1 = (const float*)d_in[30];
    const float* mlp_w2 = (const float*)d_in[31];
    const float* mlp_b2 = (const float*)d_in[32];
    const float* fin_w = (const float*)d_in[33];
    const float* fin_b = (const float*)d_in[34];

    char* base = (char*)d_ws;
    size_t off = 0;
    auto take = [&](size_t bytes) { void* p = base + off; off += (bytes + 255) & ~(size_t)255; return p; };

    float* R1 = (float*)take((size_t)CBN * CDIN * 4);  // xln planes -> xDa | xDb | xDn planes
    float* R2 = (float*)take((size_t)CBN * CDIN * 4);  // X1 planes -> KVX
    u16* w1th = (u16*)take((size_t)CDIN * CDIN * 2);
    u16* w1tm = (u16*)take((size_t)CDIN * CDIN * 2);
    u16* w2th = (u16*)take((size_t)CDIN * CD * 2);
    u16* w2tm = (u16*)take((size_t)CDIN * CD * 2);
    u16* kvth = (u16*)take((size_t)CKV * CD * 2);      // [512][256]: PkT | PvT
    u16* kvtm = (u16*)take((size_t)CKV * CD * 2);
    float* G2b  = (float*)take((size_t)2 * CD * 4);
    float* gb1b = (float*)take((size_t)CD * 4);
    float* Pq   = (float*)take((size_t)CD * CD * 4);
    float* Pg   = (float*)take((size_t)CD * 3 * CD * 4);
    float* bgv  = (float*)take((size_t)3 * CD * 4);
    float* wqbb = (float*)take((size_t)CD * 4);
    float* qwb   = (float*)take((size_t)CBS * CD * 4);
    float* qb0b  = (float*)take((size_t)CBS * 4);
    // Wacc | msumA | msumB | slotsAcc contiguous: zeroed inside mega_prep
    const int ACCN = CBS * CD * 2 + 2 * CBS * 8;
    float* Wacc  = (float*)take((size_t)ACCN * 4);
    float* msumA = Wacc + (size_t)CBS * CD;
    float* msumB = msumA + (size_t)CBS * 8;
    float* slotsAcc = msumB + (size_t)CBS * 8;
    float* giRaw = (float*)take((size_t)CBS * 3 * CD * 4);
    float* ghRaw = (float*)take((size_t)CBS * 3 * CD * 4);
    float* snewb = (float*)take((size_t)CBS * CD * 4);
    float* S_pB  = (float*)take((size_t)CBS * 2 * 4);
    float* S_sB  = (float*)take((size_t)CBS * 2 * 4);
    float* slots = (float*)take((size_t)CBS * CD * 4);
    if (ws_size < off) return;

    float* msum[2] = {msumA, msumB};

    // plane/buffer aliasing (lifetimes disjoint):
    u16* xlnh = (u16*)R1;                                  // [CBN][768] planes
    u16* xlnm = xlnh + (size_t)CBN * CDIN;
    u16* X1h  = (u16*)R2;                                  // [CBN][768] planes
    u16* X1m  = X1h + (size_t)CBN * CDIN;
    float* xDa = R1;                                       // [CBN][256] fp32 (xln dead)
    float* xDb = R1 + (size_t)CBN * CD;                    // [CBN][256] fp32 (K-half 2)
    u16* xDnh = (u16*)(R1 + (size_t)2 * CBN * CD);         // [CBN][256] planes
    u16* xDnm = xDnh + (size_t)CBN * CD;
    float* KVX = R2;                                       // [CBN][512] fp32 (X1 dead)

    float* out0 = (float*)d_out;            // [CBS,CD]
    float* attnb = out0 + CBS * CD;         // [CBS,CN]

    dim3 blk(256);
    const int gM = (CBN + 63) / 64;         // 172 M-tiles (BM=64)
    dim3 gridBN(CB, 86);                    // 8 x 86 (16 n per block)
    const int ZBLK = (ACCN + 1023) / 1024;  // accumulator-zero blocks

    // ---- fused prep: ln_planes#1 + transposes + wprep + acc-zero in one launch ----
    mega_prep_kernel<<<dim3(CBN + 768 + 1541 + ZBLK), blk, 0, stream>>>(
        inputs, xlnh, xlnm, im_ln1_g, im_ln1_b,
        im_w1, w1th, w1tm, im_w2, w2th, w2tm,
        Wk, Wv, Wq, f_w1, f_w2, kvth, kvtm, Pq,
        gru_wih, Pg, g_w, g_b, f_b1, G2b, gb1b,
        f_b2, gru_bih, bgv, wqbb, Wacc, ACCN);

    // ---- initial mlp ----
    hgemm2<128,2><<<dim3(CDIN/128, gM), blk, 0, stream>>>(xlnh, xlnm, w1th, w1tm,
        CBN, CDIN, CDIN, im_b1, 1, nullptr, X1h, X1m, nullptr);
    // split-K=2: halves to xDa/xDb (bias folded into ln_planes_sum2)
    hgemm2<64,3><<<dim3(CD/64, gM, 2), blk, 0, stream>>>(X1h, X1m, w2th, w2tm,
        CBN, CD, CDIN, nullptr, 0, xDa, nullptr, nullptr, xDb);
    ln_planes_sum2_kernel<<<CBN, blk, 0, stream>>>(xDa, xDb, im_b2,
        xDnh, xDnm, im_ln2_g, im_ln2_b);
    hgemm2<128,2><<<dim3(CKV/128, gM), blk, 0, stream>>>(xDnh, xDnm, kvth, kvtm,
        CBN, CKV, CD, nullptr, 0, KVX, nullptr, nullptr, nullptr);
    init_ln_q_kernel<<<CBS, blk, 0, stream>>>(slots_init_p, S_s0, S_p0,
        ln_g, ln_b, wqbb, Pq, slots, S_sB, S_pB, qwb, qb0b);

    for (int t = 0; t < CITERS; t++) {
        dotsv_kernel<<<gridBN, blk, 0, stream>>>(KVX, S_pB, S_sB,
            msum[(t + 1) & 1], t > 0 ? 1 : 0, G2b, gb1b,
            qwb, qb0b, nullptr, Wacc, msum[t & 1]);
        rowgemmG_kernel<<<dim3(CBS, 3*CD/128, 2), dim3(128), 0, stream>>>(
            Wacc, Pg, bgv, giRaw, slots, gru_whh, gru_bhh, ghRaw, msum[t & 1], 3 * CD, CD);
        gate_mlp1_kernel<<<dim3(CBS, 8), dim3(128), 0, stream>>>(giRaw, ghRaw, slots,
            mlp_ln_g, mlp_ln_b, mlp_w1, mlp_b1, mlp_w2, snewb, slotsAcc,
            Wacc, msum[(t + 1) & 1]);
        slotsup_kernel<<<CBS, blk, 0, stream>>>(slotsAcc, mlp_b2, snewb,
            ln_g, ln_b, wqbb, Pq, slots, qwb, qb0b);
    }
    // final: write attn (+ msum for its m0), then fused scale + out GEMV
    dotsv_kernel<<<gridBN, blk, 0, stream>>>(KVX, S_pB, S_sB,
        msum[0], 1, G2b, gb1b, qwb, qb0b, attnb, nullptr, msum[1]);
    final_kernel<<<dim3(CBS, 3), dim3(128), 0, stream>>>(slots, fin_w, fin_b,
        out0, attnb, msum[1]);
}

// Round 14
// 554.657 us; speedup vs baseline: 1.0256x; 1.0256x over previous
//
#include <hip/hip_runtime.h>

// ---------------- problem constants ----------------
constexpr int CB   = 8;      // batch
constexpr int CN   = 1369;   // tokens (37*37)
constexpr int CDIN = 768;
constexpr int CS   = 7;      // slots
constexpr int CD   = 256;
constexpr int CITERS = 3;
constexpr int CRES = 37;
constexpr float CSIGMA = 5.0f;
constexpr int CBS = CB * CS;        // 56
constexpr int CBN = CB * CN;        // 10952 rows for initial mlp
constexpr int CKV = 2 * CD;         // interleaved KX|VX row stride
constexpr float LNEPS = 1e-5f;
constexpr float ATTN_EPS = 1e-8f;

typedef unsigned short u16;
typedef short bs8 __attribute__((ext_vector_type(8)));   // 8 bf16 (bit pattern in shorts)
typedef float f4 __attribute__((ext_vector_type(4)));

// ---------------- helpers ----------------
__device__ __forceinline__ float ag_x(int n) { return -1.f + (float)(n % CRES) * (2.f / 36.f); }
__device__ __forceinline__ float ag_y(int n) { return -1.f + (float)(n / CRES) * (2.f / 36.f); }

__device__ __forceinline__ u16 bf_rne(float f) {
    unsigned u = __float_as_uint(f);
    return (u16)((u + 0x7FFFu + ((u >> 16) & 1u)) >> 16);
}
__device__ __forceinline__ float bf_to_f(u16 h) { return __uint_as_float(((unsigned)h) << 16); }

__device__ __forceinline__ void split2b(float v, u16& h, u16& m) {
    h = bf_rne(v);
    m = bf_rne(v - bf_to_f(h));
}

// async global->LDS, 16B per lane (dest = wave-uniform base + lane*16)
__device__ __forceinline__ void async16(const u16* g, u16* l) {
    __builtin_amdgcn_global_load_lds(
        (const __attribute__((address_space(1))) unsigned int*)g,
        (__attribute__((address_space(3))) unsigned int*)l, 16, 0, 0);
}

// 256-thread block sum (3 barriers)
__device__ __forceinline__ float block_reduce_sum(float v, float* sbuf) {
    #pragma unroll
    for (int off = 32; off > 0; off >>= 1) v += __shfl_down(v, off, 64);
    if ((threadIdx.x & 63) == 0) sbuf[threadIdx.x >> 6] = v;
    __syncthreads();
    if (threadIdx.x == 0) sbuf[0] = sbuf[0] + sbuf[1] + sbuf[2] + sbuf[3];
    __syncthreads();
    float r = sbuf[0];
    __syncthreads();
    return r;
}

// 256-thread joint (sum, sumsq) reduction (2 barriers). r0 keeps the same
// wave-partial summation order as block_reduce_sum.
__device__ __forceinline__ void block_reduce_sum2(float v0, float v1, float* sbuf,
        float& r0, float& r1) {
    #pragma unroll
    for (int off = 32; off > 0; off >>= 1) {
        v0 += __shfl_down(v0, off, 64);
        v1 += __shfl_down(v1, off, 64);
    }
    if ((threadIdx.x & 63) == 0) {
        sbuf[(threadIdx.x >> 6) * 2]     = v0;
        sbuf[(threadIdx.x >> 6) * 2 + 1] = v1;
    }
    __syncthreads();
    r0 = ((sbuf[0] + sbuf[2]) + sbuf[4]) + sbuf[6];
    r1 = ((sbuf[1] + sbuf[3]) + sbuf[5]) + sbuf[7];
    __syncthreads();
}

// 128-thread joint (sum, sumsq) reduction (2 barriers)
__device__ __forceinline__ void block_reduce_sum2_128(float v0, float v1, float* sbuf,
        float& r0, float& r1) {
    #pragma unroll
    for (int off = 32; off > 0; off >>= 1) {
        v0 += __shfl_down(v0, off, 64);
        v1 += __shfl_down(v1, off, 64);
    }
    if ((threadIdx.x & 63) == 0) {
        sbuf[(threadIdx.x >> 6) * 2]     = v0;
        sbuf[(threadIdx.x >> 6) * 2 + 1] = v1;
    }
    __syncthreads();
    r0 = sbuf[0] + sbuf[2];
    r1 = sbuf[1] + sbuf[3];
    __syncthreads();
}

// ---------------- layernorm (d=256) -> split-2 bf16 planes, joint reduction ----------------
__global__ __launch_bounds__(256) void ln_planes256_kernel(const float* __restrict__ in,
        u16* __restrict__ Yh, u16* __restrict__ Ym,
        const float* __restrict__ g, const float* __restrict__ b) {
    __shared__ float sbuf[8];
    int row = blockIdx.x, t = threadIdx.x;
    float x = in[(size_t)row * CD + t];
    float s, sq;
    block_reduce_sum2(x, x * x, sbuf, s, sq);
    float mean = s / CD;
    float var = fmaxf(sq / CD - mean * mean, 0.f);
    float rstd = rsqrtf(var + LNEPS);
    float y = (x - mean) * rstd * g[t] + b[t];
    u16 h, m; split2b(y, h, m);
    Yh[(size_t)row * CD + t] = h; Ym[(size_t)row * CD + t] = m;
}

// ---------------- mega prep: ln_planes(inputs,768) + transposes + wprep + accZero ----------------
// bid [0, CBN): LN row -> xln planes (joint 2-barrier reduction)
// bid [CBN, CBN+576): transpose im_w1 tile; [CBN+576, CBN+768): im_w2 tile
// bid [CBN+768, CBN+768+1541): wprep block (kv planes / Pq / Pg / g2 / bg / wqb)
// bid >= CBN+2309: zero accumulators (Wacc|msumA|msumB|slotsAcc)
__global__ __launch_bounds__(256) void mega_prep_kernel(
        const float* __restrict__ inputs, u16* __restrict__ xlnh, u16* __restrict__ xlnm,
        const float* __restrict__ im_ln1_g, const float* __restrict__ im_ln1_b,
        const float* __restrict__ im_w1, u16* __restrict__ w1th, u16* __restrict__ w1tm,
        const float* __restrict__ im_w2, u16* __restrict__ w2th, u16* __restrict__ w2tm,
        const float* __restrict__ Wk, const float* __restrict__ Wv,
        const float* __restrict__ Wq,
        const float* __restrict__ f_w1, const float* __restrict__ f_w2,
        u16* __restrict__ kvth, u16* __restrict__ kvtm, float* __restrict__ Pq,
        const float* __restrict__ wih, float* __restrict__ Pg,
        const float* __restrict__ g_w, const float* __restrict__ g_b,
        const float* __restrict__ f_b1,
        float* __restrict__ G2, float* __restrict__ gb1,
        const float* __restrict__ f_b2, const float* __restrict__ bih,
        float* __restrict__ bg, float* __restrict__ wqb,
        float* __restrict__ accZ, int accN) {
    __shared__ float shm[1056];        // union: sbuf[8] | tile[32][33] | arow[256]
    int bid = blockIdx.x;
    int t = threadIdx.x;
    if (bid < CBN) {
        // ---- ln_planes d=768 (joint reduction) ----
        int row = bid;
        const float* x = inputs + (size_t)row * CDIN;
        float v0 = x[t], v1 = x[t + 256], v2 = x[t + 512];
        float s, sq;
        block_reduce_sum2(v0 + v1 + v2, v0 * v0 + v1 * v1 + v2 * v2, shm, s, sq);
        float mean = s / CDIN;
        float var = fmaxf(sq / CDIN - mean * mean, 0.f);
        float rstd = rsqrtf(var + LNEPS);
        u16 h, m;
        float y = (v0 - mean) * rstd * im_ln1_g[t] + im_ln1_b[t];
        split2b(y, h, m);
        xlnh[(size_t)row * CDIN + t] = h; xlnm[(size_t)row * CDIN + t] = m;
        float y1 = (v1 - mean) * rstd * im_ln1_g[t + 256] + im_ln1_b[t + 256];
        split2b(y1, h, m);
        xlnh[(size_t)row * CDIN + t + 256] = h; xlnm[(size_t)row * CDIN + t + 256] = m;
        float y2 = (v2 - mean) * rstd * im_ln1_g[t + 512] + im_ln1_b[t + 512];
        split2b(y2, h, m);
        xlnh[(size_t)row * CDIN + t + 512] = h; xlnm[(size_t)row * CDIN + t + 512] = m;
        return;
    }
    if (bid < CBN + 768) {
        // ---- transpose_split2 ----
        int tb = bid - CBN;
        const float* W; u16 *Th, *Tm; int N, bx, by;
        if (tb < 576) { W = im_w1; Th = w1th; Tm = w1tm; N = CDIN; bx = tb % 24; by = tb / 24; }
        else { tb -= 576; W = im_w2; Th = w2th; Tm = w2tm; N = CD; bx = tb % 8; by = tb / 8; }
        int K = CDIN;
        float (*tile)[33] = (float(*)[33])shm;
        int nb = bx * 32, kb = by * 32;
        int tx = t & 31, ty = t >> 5;
        #pragma unroll
        for (int i = 0; i < 32; i += 8)
            tile[ty + i][tx] = W[(size_t)(kb + ty + i) * N + nb + tx];
        __syncthreads();
        #pragma unroll
        for (int i = 0; i < 32; i += 8) {
            float v = tile[tx][ty + i];
            u16 h, m; split2b(v, h, m);
            size_t idx = (size_t)(nb + ty + i) * K + kb + tx;
            Th[idx] = h; Tm[idx] = m;
        }
        return;
    }
    if (bid >= CBN + 768 + 1541) {
        // ---- zero accumulators ----
        int zb = bid - (CBN + 768 + 1541);
        int fi = (zb * 256 + t) * 4;
        if (fi + 3 < accN) *(f4*)(accZ + fi) = (f4){0.f, 0.f, 0.f, 0.f};
        else for (int i = fi; i < accN; i++) accZ[i] = 0.f;
        return;
    }
    // ---- wprep ----
    int wb = bid - CBN - 768;
    float* arow = shm;
    int n = t;
    if (wb < 512) {
        const float* A = (wb < 256) ? Wk : Wv;
        int k = wb & 255;
        size_t poff = (wb < 256) ? 0 : (size_t)CD * CD;
        arow[n] = A[k * CD + n];
        __syncthreads();
        float acc = 0.f;
        for (int j = 0; j < CD; j++) acc += arow[j] * f_w1[(size_t)j * CD + n];
        u16 h, m; split2b(acc, h, m);
        kvth[poff + (size_t)n * CD + k] = h;
        kvtm[poff + (size_t)n * CD + k] = m;
    } else if (wb < 768) {
        int k = wb - 512;
        arow[n] = Wq[k * CD + n];
        __syncthreads();
        float acc = 0.f;
        for (int c = 0; c < CD; c++) acc += arow[c] * f_w2[(size_t)n * CD + c];
        Pq[(size_t)k * CD + n] = acc;
    } else if (wb < 1536) {
        int wb2 = wb - 768;
        int k = wb2 & 255;
        int ny = wb2 >> 8;
        arow[n] = f_w2[k * CD + n];
        __syncthreads();
        int nn = ny * 256 + n;
        float acc = 0.f;
        for (int j = 0; j < CD; j++) acc += arow[j] * wih[(size_t)j * (3 * CD) + nn];
        Pg[(size_t)k * (3 * CD) + nn] = acc;
    } else if (wb == 1536) {
        float a0 = 0.f, a1 = 0.f, ab = 0.f;
        for (int j = 0; j < CD; j++) {
            float w = f_w1[j * CD + n];
            a0 += g_w[j] * w;
            a1 += g_w[CD + j] * w;
            ab += g_b[j] * w;
        }
        G2[n] = a0; G2[CD + n] = a1; gb1[n] = ab + f_b1[n];
    } else if (wb <= 1539) {
        int nn = (wb - 1537) * 256 + n;
        float s = bih[nn];
        for (int c = 0; c < CD; c++) s += f_b2[c] * wih[(size_t)c * (3 * CD) + nn];
        bg[nn] = s;
    } else {
        float s = 0.f;
        for (int c = 0; c < CD; c++) s += Wq[n * CD + c] * f_b2[c];
        wqb[n] = s;
    }
}

// ---------------- bf16x3 plane GEMM, BM=64 x BN, NBUF-deep counted-vmcnt pipeline ----------------
// #1: BN=128, NBUF=2 (proven ~68-70us). #2: BN=64, NBUF=3. #3: BN=128, NBUF=2.
// LDS slot swizzle via inverse-permuted global source; bijective XCD swizzle.
// NOTE: SQ_LDS_BANK_CONFLICT ~= 8 cyc per global_load_lds wave-issue is the
// structural LDS-write transfer time (1024B / 128B-per-cyc), not fixable.
template<int BN, int NBUF>
__global__ __launch_bounds__(256)
void hgemm2(const u16* __restrict__ Ah, const u16* __restrict__ Am,
            const u16* __restrict__ Bh, const u16* __restrict__ Bm,
            int M, int N, int K, const float* __restrict__ bias, int relu,
            float* __restrict__ Cf, u16* __restrict__ Ch, u16* __restrict__ Cm) {
    constexpr int BP = BN * 32;            // u16 per B plane
    constexpr int SB = 4096 + 2 * BP;      // u16 per LDS buffer
    constexpr int NI = 2 + 2 * (BN / 64);  // staging issues per k-step: 6 or 4
    constexpr int NF = BN / 32;            // B frags per wave: 4 or 2
    constexpr int PP = BN / 64;            // issues per B plane: 2 or 1
    __shared__ u16 smem[NBUF][SB];
    const int tid = threadIdx.x;

    int bx = blockIdx.x, by = blockIdx.y;
    {
        int gx = gridDim.x;
        int nwg = gx * gridDim.y;
        if (!(nwg & 7)) {               // XCD-aware swizzle (bijective, nwg%8==0)
            int bid = by * gx + bx;
            int cpx = nwg >> 3;
            int s = (bid & 7) * cpx + (bid >> 3);
            bx = s % gx; by = s / gx;
        }
    }
    const int m0 = by * 64, n0 = bx * BN;
    const int w = tid >> 6, lane = tid & 63;
    const int wm = w & 1, wn = w >> 1;
    const int l15 = lane & 15, l4 = lane >> 4;

    // staging map: i0=Ah, i1=Am, then B planes (PP issues each)
    const u16* srcp[NI];
    int dsto[NI];
    #pragma unroll
    for (int i = 0; i < NI; i++) {
        const u16* bp; int row, r, c;
        if (i < 2) {                       // A planes: 64 rows x 4 chunks = 256
            int qq = tid;
            r = qq >> 2;
            c = (qq & 3) ^ ((r ^ (r >> 2)) & 3);   // inverse swizzle on source
            bp = (i == 0) ? Ah : Am;
            row = m0 + r; row = row < M ? row : M - 1;
            dsto[i] = i * 2048 + w * 512;
        } else {                           // B planes: BN rows x 4 chunks
            int ii = i - 2;
            int plane = ii / PP;           // 0:Bh 1:Bm
            int sub = ii % PP;
            int qq = sub * 256 + tid;
            r = qq >> 2;
            c = (qq & 3) ^ ((r ^ (r >> 2)) & 3);
            bp = plane ? Bm : Bh;
            row = n0 + r;
            dsto[i] = 4096 + plane * BP + sub * 2048 + w * 512;
        }
        srcp[i] = bp + (size_t)row * K + c * 8;
    }

    f4 acc[2][NF];
    #pragma unroll
    for (int i = 0; i < 2; i++)
        #pragma unroll
        for (int j = 0; j < NF; j++) acc[i][j] = (f4){0.f, 0.f, 0.f, 0.f};

    // swizzled k-chunk slot for fragment reads
    const int cx8 = (l4 ^ (l15 & 3) ^ ((l15 >> 2) & 3)) * 8;

    const int ns = K / 32;
    // prologue: stage steps 0..D-1 (no drain)
    #pragma unroll
    for (int d = 0; d < NBUF - 1; d++)
        #pragma unroll
        for (int i = 0; i < NI; i++) async16(srcp[i] + d * 32, &smem[d][dsto[i]]);

    u16* c0 = &smem[0][0];
    u16* c1 = &smem[NBUF > 1 ? 1 : 0][0];
    u16* c2 = &smem[NBUF - 1][0];

    for (int k = 0; k < ns; k++) {
        if constexpr (NBUF == 3) {
            if (k + 2 < ns) {
                #pragma unroll
                for (int i = 0; i < NI; i++) async16(srcp[i] + (k + 2) * 32, c2 + dsto[i]);
                if constexpr (BN == 64) asm volatile("s_waitcnt vmcnt(8)" ::: "memory");
                else                     asm volatile("s_waitcnt vmcnt(12)" ::: "memory");
            } else if (k + 1 < ns) {
                if constexpr (BN == 64) asm volatile("s_waitcnt vmcnt(4)" ::: "memory");
                else                     asm volatile("s_waitcnt vmcnt(6)" ::: "memory");
            } else {
                asm volatile("s_waitcnt vmcnt(0)" ::: "memory");
            }
        } else {
            if (k + 1 < ns) {
                #pragma unroll
                for (int i = 0; i < NI; i++) async16(srcp[i] + (k + 1) * 32, c1 + dsto[i]);
                if constexpr (BN == 64) asm volatile("s_waitcnt vmcnt(4)" ::: "memory");
                else                     asm volatile("s_waitcnt vmcnt(6)" ::: "memory");
            } else {
                asm volatile("s_waitcnt vmcnt(0)" ::: "memory");
            }
        }
        __builtin_amdgcn_s_barrier();        // all threads' step-k loads landed
        bs8 ah[2], am[2], bh[NF], bm[NF];
        #pragma unroll
        for (int f = 0; f < 2; f++) {
            int oa = (wm * 32 + f * 16 + l15) * 32 + cx8;
            ah[f] = *(const bs8*)(c0 + oa);
            am[f] = *(const bs8*)(c0 + 2048 + oa);
        }
        #pragma unroll
        for (int f = 0; f < NF; f++) {
            int ob = (wn * (NF * 16) + f * 16 + l15) * 32 + cx8;
            bh[f] = *(const bs8*)(c0 + 4096 + ob);
            bm[f] = *(const bs8*)(c0 + 4096 + BP + ob);
        }
        #pragma unroll
        for (int mf = 0; mf < 2; mf++)
            #pragma unroll
            for (int nf = 0; nf < NF; nf++) {
                acc[mf][nf] = __builtin_amdgcn_mfma_f32_16x16x32_bf16(am[mf], bh[nf], acc[mf][nf], 0, 0, 0);
                acc[mf][nf] = __builtin_amdgcn_mfma_f32_16x16x32_bf16(ah[mf], bm[nf], acc[mf][nf], 0, 0, 0);
                acc[mf][nf] = __builtin_amdgcn_mfma_f32_16x16x32_bf16(ah[mf], bh[nf], acc[mf][nf], 0, 0, 0);
            }
        asm volatile("" ::: "memory");       // keep LDS reads ordered vs barrier
        __builtin_amdgcn_s_barrier();        // all done reading c0 (no vmcnt drain!)
        if constexpr (NBUF == 3) { u16* t_ = c0; c0 = c1; c1 = c2; c2 = t_; }
        else                     { u16* t_ = c0; c0 = c1; c1 = t_; }
    }

    #pragma unroll
    for (int mf = 0; mf < 2; mf++)
        #pragma unroll
        for (int i = 0; i < 4; i++) {
            int grow = m0 + wm * 32 + mf * 16 + l4 * 4 + i;
            if (grow < M) {
                #pragma unroll
                for (int nf = 0; nf < NF; nf++) {
                    int col = n0 + wn * (NF * 16) + nf * 16 + l15;
                    float v = acc[mf][nf][i] + (bias ? bias[col] : 0.f);
                    if (relu) v = fmaxf(v, 0.f);
                    if (Cf) Cf[(size_t)grow * N + col] = v;
                    else {
                        u16 h, m; split2b(v, h, m);
                        Ch[(size_t)grow * N + col] = h;
                        Cm[(size_t)grow * N + col] = m;
                    }
                }
            }
        }
}

// gi/gh pair in one launch via blockIdx.z; z==0 rows scaled by 1/m0 (from msum)
__global__ __launch_bounds__(128) void rowgemmG_kernel(
        const float* __restrict__ A0, const float* __restrict__ W0,
        const float* __restrict__ b0, float* __restrict__ C0,
        const float* __restrict__ A1, const float* __restrict__ W1,
        const float* __restrict__ b1, float* __restrict__ C1,
        const float* __restrict__ msum, int N, int K) {
    __shared__ float sA[256];
    const float* A = blockIdx.z ? A1 : A0;
    const float* W = blockIdx.z ? W1 : W0;
    const float* B = blockIdx.z ? b1 : b0;
    float* C = blockIdx.z ? C1 : C0;
    int r = blockIdx.x;
    int c = blockIdx.y * 128 + threadIdx.x;
    float scl = blockIdx.z ? 1.f : 1.f / msum[r * 8];
    for (int i = threadIdx.x; i < K; i += 128) sA[i] = A[(size_t)r * K + i] * scl;
    __syncthreads();
    float a0 = 0.f, a1 = 0.f, a2 = 0.f, a3 = 0.f;
    #pragma unroll 4
    for (int k = 0; k < K; k += 4) {
        a0 += sA[k]     * W[(size_t)k * N + c];
        a1 += sA[k + 1] * W[(size_t)(k + 1) * N + c];
        a2 += sA[k + 2] * W[(size_t)(k + 2) * N + c];
        a3 += sA[k + 3] * W[(size_t)(k + 3) * N + c];
    }
    C[(size_t)r * N + c] = (a0 + a1) + (a2 + a3) + B[c];
}

// ---------------- fused init: slots broadcast + S init + LN + qb0 + qw (t=0) ----------------
__global__ __launch_bounds__(256) void init_ln_q_kernel(const float* __restrict__ slots_init_p,
        const float* __restrict__ S_s0, const float* __restrict__ S_p0,
        const float* __restrict__ ln_g, const float* __restrict__ ln_b,
        const float* __restrict__ wqb, const float* __restrict__ Pq,
        float* __restrict__ slots, float* __restrict__ S_s, float* __restrict__ S_p,
        float* __restrict__ qwb, float* __restrict__ qb0) {
    __shared__ float sbuf[8];
    __shared__ float sN[CD];
    int row = blockIdx.x, t = threadIdx.x;
    int s = row % CS;
    float x = slots_init_p[s * CD + t];
    slots[row * CD + t] = x;
    if (t < 2) { S_s[row * 2 + t] = S_s0[s * 2 + t]; S_p[row * 2 + t] = S_p0[s * 2 + t]; }
    float sm, sq;
    block_reduce_sum2(x, x * x, sbuf, sm, sq);
    float mean = sm / CD;
    float var = fmaxf(sq / CD - mean * mean, 0.f);
    float sn = (x - mean) * rsqrtf(var + LNEPS) * ln_g[t] + ln_b[t];
    sN[t] = sn;
    float qb = block_reduce_sum(sn * wqb[t], sbuf);
    if (t == 0) qb0[row] = qb;
    __syncthreads();
    float acc = 0.f;
    #pragma unroll 4
    for (int k = 0; k < CD; k++) acc += sN[k] * Pq[(size_t)k * CD + t];
    qwb[row * CD + t] = acc;
}

// fused slots finalize: slots = snew + b2 + slotsAcc (w2 GEMV pre-accumulated by
// gate_mlp1 via atomics); zero slotsAcc for next iter; LN + qb0 + qw GEMV.
__global__ __launch_bounds__(256) void slotsup_kernel(float* __restrict__ slotsAcc,
        const float* __restrict__ b2, const float* __restrict__ snewb,
        const float* __restrict__ ln_g, const float* __restrict__ ln_b,
        const float* __restrict__ wqb, const float* __restrict__ Pq,
        float* __restrict__ slots, float* __restrict__ qwb, float* __restrict__ qb0) {
    __shared__ float sbuf[8];
    __shared__ float sN[CD];
    int row = blockIdx.x, t = threadIdx.x;
    float v = snewb[row * CD + t] + b2[t] + slotsAcc[row * CD + t];
    slotsAcc[row * CD + t] = 0.f;          // ready for next iteration's atomics
    slots[row * CD + t] = v;
    float sm, sq;
    block_reduce_sum2(v, v * v, sbuf, sm, sq);
    float mean = sm / CD;
    float var = fmaxf(sq / CD - mean * mean, 0.f);
    float sn = (v - mean) * rsqrtf(var + LNEPS) * ln_g[t] + ln_b[t];
    sN[t] = sn;
    float qb = block_reduce_sum(sn * wqb[t], sbuf);
    if (t == 0) qb0[row] = qb;
    __syncthreads();
    float acc = 0.f;
    #pragma unroll 4
    for (int k = 0; k < CD; k++) acc += sN[k] * Pq[(size_t)k * CD + t];
    qwb[row * CD + t] = acc;
}

// dots + softmax-over-slots + (optional) vsum + (optional) fused moments.
// Moments are lane-distributed: lanes 0-34 each own one (slot, moment) pair.
__global__ __launch_bounds__(256) void dotsv_kernel(const float* __restrict__ KVX,
        const float* __restrict__ S_p, const float* __restrict__ S_s,
        const float* __restrict__ msum_in, int useMsum,
        const float* __restrict__ G2, const float* __restrict__ gb1,
        const float* __restrict__ qw, const float* __restrict__ qb0,
        float* __restrict__ attn, float* __restrict__ Wacc,
        float* __restrict__ msum_out) {
    __shared__ float sred[4 * CD];
    int b = blockIdx.x;
    int w = threadIdx.x >> 6, l = threadIdx.x & 63;
    int k4 = l * 4;
    float4 g0 = *(const float4*)(G2 + k4);
    float4 g1 = *(const float4*)(G2 + CD + k4);
    float4 gb = *(const float4*)(gb1 + k4);
    float4 qwv[CS]; float px[CS], py[CS], ix[CS], iy[CS], q0[CS];
    #pragma unroll
    for (int s = 0; s < CS; s++) {
        int bs = b * CS + s;
        qwv[s] = *(const float4*)(qw + bs * CD + k4);
        if (useMsum) {
            const float* mp = msum_in + bs * 8;
            float m0 = mp[0];
            float pxv = mp[1] / m0, pyv = mp[2] / m0;
            float sx = sqrtf(fmaxf(mp[3] / m0 - pxv * pxv, 0.f));
            float sy = sqrtf(fmaxf(mp[4] / m0 - pyv * pyv, 0.f));
            px[s] = pxv; py[s] = pyv;
            ix[s] = 1.f / (sx * CSIGMA); iy[s] = 1.f / (sy * CSIGMA);
        } else {
            px[s] = S_p[2 * bs]; py[s] = S_p[2 * bs + 1];
            ix[s] = 1.f / (S_s[2 * bs] * CSIGMA); iy[s] = 1.f / (S_s[2 * bs + 1] * CSIGMA);
        }
        q0[s] = qb0[bs];
    }
    float4 acc[CS];
    #pragma unroll
    for (int s = 0; s < CS; s++) acc[s] = make_float4(0.f, 0.f, 0.f, 0.f);
    float wmv = 0.f;
    int sidx = l / 5;
    int jidx = l - sidx * 5;
    int nbase = blockIdx.y * 16 + w * 4;
    #pragma unroll
    for (int i = 0; i < 4; i++) {
        int n = nbase + i;
        int nc = n < CN ? n : CN - 1;
        const float* rowp = KVX + (size_t)(b * CN + nc) * CKV;
        float4 kx = *(const float4*)(rowp + k4);
        float ax = ag_x(nc), ay = ag_y(nc);
        float dsv[CS];
        #pragma unroll
        for (int s = 0; s < CS; s++) {
            float r0 = (ax - px[s]) * ix[s];
            float r1 = (ay - py[s]) * iy[s];
            float v0 = fmaxf(kx.x + r0 * g0.x + r1 * g1.x + gb.x, 0.f);
            float v1 = fmaxf(kx.y + r0 * g0.y + r1 * g1.y + gb.y, 0.f);
            float v2 = fmaxf(kx.z + r0 * g0.z + r1 * g1.z + gb.z, 0.f);
            float v3 = fmaxf(kx.w + r0 * g0.w + r1 * g1.w + gb.w, 0.f);
            float d = v0 * qwv[s].x + v1 * qwv[s].y + v2 * qwv[s].z + v3 * qwv[s].w;
            #pragma unroll
            for (int off = 32; off > 0; off >>= 1) d += __shfl_xor(d, off, 64);
            dsv[s] = 0.0625f * (d + q0[s]);
        }
        float mx = -1e30f;
        #pragma unroll
        for (int s = 0; s < CS; s++) mx = fmaxf(mx, dsv[s]);
        float sum = 0.f;
        #pragma unroll
        for (int s = 0; s < CS; s++) { dsv[s] = __expf(dsv[s] - mx); sum += dsv[s]; }
        float inv = 1.f / sum;
        #pragma unroll
        for (int s = 0; s < CS; s++) dsv[s] = dsv[s] * inv + ATTN_EPS;
        if (attn && l == 0 && n < CN) {
            #pragma unroll
            for (int s = 0; s < CS; s++)
                attn[(size_t)(b * CS + s) * CN + n] = dsv[s];
        }
        if (msum_out && n < CN) {
            float ax2 = ax * ax, ay2 = ay * ay;
            float a = dsv[0];
            a = (sidx == 1) ? dsv[1] : a;
            a = (sidx == 2) ? dsv[2] : a;
            a = (sidx == 3) ? dsv[3] : a;
            a = (sidx == 4) ? dsv[4] : a;
            a = (sidx == 5) ? dsv[5] : a;
            a = (sidx == 6) ? dsv[6] : a;
            float coef = 1.f;
            coef = (jidx == 1) ? ax : coef;
            coef = (jidx == 2) ? ay : coef;
            coef = (jidx == 3) ? ax2 : coef;
            coef = (jidx == 4) ? ay2 : coef;
            wmv += a * coef;
        }
        if (Wacc && n < CN) {
            float4 vx = *(const float4*)(rowp + CD + k4);
            #pragma unroll
            for (int s = 0; s < CS; s++) {
                float r0 = (ax - px[s]) * ix[s];
                float r1 = (ay - py[s]) * iy[s];
                float a = dsv[s];
                acc[s].x += a * fmaxf(vx.x + r0 * g0.x + r1 * g1.x + gb.x, 0.f);
                acc[s].y += a * fmaxf(vx.y + r0 * g0.y + r1 * g1.y + gb.y, 0.f);
                acc[s].z += a * fmaxf(vx.z + r0 * g0.z + r1 * g1.z + gb.z, 0.f);
                acc[s].w += a * fmaxf(vx.w + r0 * g0.w + r1 * g1.w + gb.w, 0.f);
            }
        }
    }
    if (Wacc) {
        for (int s = 0; s < CS; s++) {
            ((float4*)sred)[w * 64 + l] = acc[s];
            __syncthreads();
            if (threadIdx.x < CD) {
                float v = sred[threadIdx.x] + sred[CD + threadIdx.x]
                        + sred[2 * CD + threadIdx.x] + sred[3 * CD + threadIdx.x];
                atomicAdd(&Wacc[(size_t)(b * CS + s) * CD + threadIdx.x], v);
            }
            __syncthreads();
        }
    }
    if (msum_out) {
        if (l < 35) sred[w * 35 + l] = wmv;
        __syncthreads();
        if (threadIdx.x < 35) {
            float v = sred[threadIdx.x] + sred[35 + threadIdx.x]
                    + sred[70 + threadIdx.x] + sred[105 + threadIdx.x];
            int s = threadIdx.x / 5, j = threadIdx.x % 5;
            atomicAdd(&msum_out[(size_t)(b * CS + s) * 8 + j], v);
        }
    }
}

// fused GRU gate + LN + h1 GEMV + partial slots GEMV (h1 @ w2 accumulated into
// slotsAcc via atomics). Grid (CBS, 8) x 128 threads; h1 never hits memory.
__global__ __launch_bounds__(128) void gate_mlp1_kernel(const float* __restrict__ giRaw,
        const float* __restrict__ ghRaw, const float* __restrict__ slots,
        const float* __restrict__ mg, const float* __restrict__ mb,
        const float* __restrict__ mlp_w1, const float* __restrict__ mlp_b1,
        const float* __restrict__ w2,
        float* __restrict__ snewb, float* __restrict__ slotsAcc,
        float* __restrict__ WaccZ, float* __restrict__ msumZ) {
    __shared__ float sbuf[4];
    __shared__ float sM[CD];
    __shared__ float sH1[128];
    int row = blockIdx.x, t = threadIdx.x;
    float snew[2];
    #pragma unroll
    for (int e = 0; e < 2; e++) {
        int tt = t + e * 128;
        float gi0 = giRaw[row * 3 * CD + tt];
        float gi1 = giRaw[row * 3 * CD + CD + tt];
        float gi2 = giRaw[row * 3 * CD + 2 * CD + tt];
        float gh0 = ghRaw[row * 3 * CD + tt];
        float gh1 = ghRaw[row * 3 * CD + CD + tt];
        float gh2 = ghRaw[row * 3 * CD + 2 * CD + tt];
        float r = 1.f / (1.f + expf(-(gi0 + gh0)));
        float z = 1.f / (1.f + expf(-(gi1 + gh1)));
        float nn = tanhf(gi2 + r * gh2);
        snew[e] = (1.f - z) * nn + z * slots[row * CD + tt];
    }
    if (blockIdx.y == 0) {
        snewb[row * CD + t] = snew[0];
        snewb[row * CD + t + 128] = snew[1];
        WaccZ[row * CD + t] = 0.f;
        WaccZ[row * CD + t + 128] = 0.f;
        if (t < 8) msumZ[row * 8 + t] = 0.f;
    }
    float sm, sq;
    block_reduce_sum2_128(snew[0] + snew[1],
        snew[0] * snew[0] + snew[1] * snew[1], sbuf, sm, sq);
    float mean = sm / CD;
    float var = fmaxf(sq / CD - mean * mean, 0.f);
    float rstd = rsqrtf(var + LNEPS);
    sM[t]       = (snew[0] - mean) * rstd * mg[t] + mb[t];
    sM[t + 128] = (snew[1] - mean) * rstd * mg[t + 128] + mb[t + 128];
    __syncthreads();
    int c = blockIdx.y * 128 + t;
    float a0 = 0.f, a1 = 0.f, a2 = 0.f, a3 = 0.f;
    #pragma unroll 4
    for (int k = 0; k < CD; k += 4) {
        a0 += sM[k]     * mlp_w1[(size_t)k * (4 * CD) + c];
        a1 += sM[k + 1] * mlp_w1[(size_t)(k + 1) * (4 * CD) + c];
        a2 += sM[k + 2] * mlp_w1[(size_t)(k + 2) * (4 * CD) + c];
        a3 += sM[k + 3] * mlp_w1[(size_t)(k + 3) * (4 * CD) + c];
    }
    sH1[t] = fmaxf((a0 + a1) + (a2 + a3) + mlp_b1[c], 0.f);
    __syncthreads();
    // partial slots GEMV over this block's 128 h1 values (k = by*128 + cc)
    float p0 = 0.f, p1 = 0.f;
    const float* w2b = w2 + (size_t)blockIdx.y * 128 * CD;
    #pragma unroll 4
    for (int cc = 0; cc < 128; cc++) {
        float h = sH1[cc];
        p0 += h * w2b[(size_t)cc * CD + t];
        p1 += h * w2b[(size_t)cc * CD + t + 128];
    }
    atomicAdd(&slotsAcc[row * CD + t], p0);
    atomicAdd(&slotsAcc[row * CD + t + 128], p1);
}

// fused final: by<2 -> out0 = slots @ fin_w + fin_b (128 cols each);
// by==2 -> attn row scale by 1/m0.
__global__ __launch_bounds__(128) void final_kernel(const float* __restrict__ slots,
        const float* __restrict__ fin_w, const float* __restrict__ fin_b,
        float* __restrict__ out0, float* __restrict__ attn,
        const float* __restrict__ msum) {
    int row = blockIdx.x;
    if (blockIdx.y == 2) {
        float inv = 1.f / msum[(size_t)row * 8];
        float* up = attn + (size_t)row * CN;
        for (int n = threadIdx.x; n < CN; n += 128) up[n] *= inv;
        return;
    }
    __shared__ float sA[CD];
    for (int i = threadIdx.x; i < CD; i += 128) sA[i] = slots[(size_t)row * CD + i];
    __syncthreads();
    int c = blockIdx.y * 128 + threadIdx.x;
    float a0 = 0.f, a1 = 0.f, a2 = 0.f, a3 = 0.f;
    #pragma unroll 4
    for (int k = 0; k < CD; k += 4) {
        a0 += sA[k]     * fin_w[(size_t)k * CD + c];
        a1 += sA[k + 1] * fin_w[(size_t)(k + 1) * CD + c];
        a2 += sA[k + 2] * fin_w[(size_t)(k + 2) * CD + c];
        a3 += sA[k + 3] * fin_w[(size_t)(k + 3) * CD + c];
    }
    out0[(size_t)row * CD + c] = (a0 + a1) + (a2 + a3) + fin_b[c];
}

// ---------------- launcher ----------------
extern "C" void kernel_launch(void* const* d_in, const int* in_sizes, int n_in,
                              void* d_out, int out_size, void* d_ws, size_t ws_size,
                              hipStream_t stream) {
    (void)in_sizes; (void)n_in; (void)out_size;
    const float* inputs       = (const float*)d_in[0];
    const float* slots_init_p = (const float*)d_in[1];
    const float* S_s0         = (const float*)d_in[2];
    const float* S_p0         = (const float*)d_in[3];
    const float* im_ln1_g = (const float*)d_in[4];
    const float* im_ln1_b = (const float*)d_in[5];
    const float* im_w1    = (const float*)d_in[6];
    const float* im_b1    = (const float*)d_in[7];
    const float* im_w2    = (const float*)d_in[8];
    const float* im_b2    = (const float*)d_in[9];
    const float* im_ln2_g = (const float*)d_in[10];
    const float* im_ln2_b = (const float*)d_in[11];
    const float* Wq  = (const float*)d_in[12];
    const float* Wk  = (const float*)d_in[13];
    const float* Wv  = (const float*)d_in[14];
    const float* g_w = (const float*)d_in[15];
    const float* g_b = (const float*)d_in[16];
    const float* f_w1 = (const float*)d_in[17];
    const float* f_b1 = (const float*)d_in[18];
    const float* f_w2 = (const float*)d_in[19];
    const float* f_b2 = (const float*)d_in[20];
    const float* ln_g = (const float*)d_in[21];
    const float* ln_b = (const float*)d_in[22];
    const float* gru_wih = (const float*)d_in[23];
    const float* gru_whh = (const float*)d_in[24];
    const float* gru_bih = (const float*)d_in[25];
    const float* gru_bhh = (const float*)d_in[26];
    const float* mlp_ln_g = (const float*)d_in[27];
    const float* mlp_ln_b = (const float*)d_in[28];
    const float* mlp_w1 = (const float*)d_in[29];
    const float* mlp_b1 = (const float*)d_in[30];
    const float* mlp_w2 = (const float*)d_in[31];
    const float* mlp_b2 = (const float*)d_in[32];
    const float* fin_w = (const float*)d_in[33];
    const float* fin_b = (const float*)d_in[34];

    char* base = (char*)d_ws;
    size_t off = 0;
    auto take = [&](size_t bytes) { void* p = base + off; off += (bytes + 255) & ~(size_t)255; return p; };

    float* R1 = (float*)take((size_t)CBN * CDIN * 4);  // xln planes -> xD | xDn planes
    float* R2 = (float*)take((size_t)CBN * CDIN * 4);  // X1 planes -> KVX
    u16* w1th = (u16*)take((size_t)CDIN * CDIN * 2);
    u16* w1tm = (u16*)take((size_t)CDIN * CDIN * 2);
    u16* w2th = (u16*)take((size_t)CDIN * CD * 2);
    u16* w2tm = (u16*)take((size_t)CDIN * CD * 2);
    u16* kvth = (u16*)take((size_t)CKV * CD * 2);      // [512][256]: PkT | PvT
    u16* kvtm = (u16*)take((size_t)CKV * CD * 2);
    float* G2b  = (float*)take((size_t)2 * CD * 4);
    float* gb1b = (float*)take((size_t)CD * 4);
    float* Pq   = (float*)take((size_t)CD * CD * 4);
    float* Pg   = (float*)take((size_t)CD * 3 * CD * 4);
    float* bgv  = (float*)take((size_t)3 * CD * 4);
    float* wqbb = (float*)take((size_t)CD * 4);
    float* qwb   = (float*)take((size_t)CBS * CD * 4);
    float* qb0b  = (float*)take((size_t)CBS * 4);
    // Wacc | msumA | msumB | slotsAcc contiguous: zeroed inside mega_prep
    const int ACCN = CBS * CD * 2 + 2 * CBS * 8;
    float* Wacc  = (float*)take((size_t)ACCN * 4);
    float* msumA = Wacc + (size_t)CBS * CD;
    float* msumB = msumA + (size_t)CBS * 8;
    float* slotsAcc = msumB + (size_t)CBS * 8;
    float* giRaw = (float*)take((size_t)CBS * 3 * CD * 4);
    float* ghRaw = (float*)take((size_t)CBS * 3 * CD * 4);
    float* snewb = (float*)take((size_t)CBS * CD * 4);
    float* S_pB  = (float*)take((size_t)CBS * 2 * 4);
    float* S_sB  = (float*)take((size_t)CBS * 2 * 4);
    float* slots = (float*)take((size_t)CBS * CD * 4);
    if (ws_size < off) return;

    float* msum[2] = {msumA, msumB};

    // plane/buffer aliasing (lifetimes disjoint):
    u16* xlnh = (u16*)R1;                                  // [CBN][768] planes
    u16* xlnm = xlnh + (size_t)CBN * CDIN;
    u16* X1h  = (u16*)R2;                                  // [CBN][768] planes
    u16* X1m  = X1h + (size_t)CBN * CDIN;
    float* xD = R1;                                        // [CBN][256] fp32 (xln dead)
    u16* xDnh = (u16*)(R1 + (size_t)CBN * CD);             // [CBN][256] planes
    u16* xDnm = xDnh + (size_t)CBN * CD;
    float* KVX = R2;                                       // [CBN][512] fp32 (X1 dead)

    float* out0 = (float*)d_out;            // [CBS,CD]
    float* attnb = out0 + CBS * CD;         // [CBS,CN]

    dim3 blk(256);
    const int gM = (CBN + 63) / 64;         // 172 M-tiles (BM=64)
    dim3 gridBN(CB, 86);                    // 8 x 86 (16 n per block)
    const int ZBLK = (ACCN + 1023) / 1024;  // accumulator-zero blocks

    // ---- fused prep: ln_planes#1 + transposes + wprep + acc-zero in one launch ----
    mega_prep_kernel<<<dim3(CBN + 768 + 1541 + ZBLK), blk, 0, stream>>>(
        inputs, xlnh, xlnm, im_ln1_g, im_ln1_b,
        im_w1, w1th, w1tm, im_w2, w2th, w2tm,
        Wk, Wv, Wq, f_w1, f_w2, kvth, kvtm, Pq,
        gru_wih, Pg, g_w, g_b, f_b1, G2b, gb1b,
        f_b2, gru_bih, bgv, wqbb, Wacc, ACCN);

    // ---- initial mlp ----
    hgemm2<128,2><<<dim3(CDIN/128, gM), blk, 0, stream>>>(xlnh, xlnm, w1th, w1tm,
        CBN, CDIN, CDIN, im_b1, 1, nullptr, X1h, X1m);
    hgemm2<64,3><<<dim3(CD/64, gM), blk, 0, stream>>>(X1h, X1m, w2th, w2tm,
        CBN, CD, CDIN, im_b2, 0, xD, nullptr, nullptr);
    ln_planes256_kernel<<<CBN, blk, 0, stream>>>(xD, xDnh, xDnm, im_ln2_g, im_ln2_b);
    hgemm2<128,2><<<dim3(CKV/128, gM), blk, 0, stream>>>(xDnh, xDnm, kvth, kvtm,
        CBN, CKV, CD, nullptr, 0, KVX, nullptr, nullptr);
    init_ln_q_kernel<<<CBS, blk, 0, stream>>>(slots_init_p, S_s0, S_p0,
        ln_g, ln_b, wqbb, Pq, slots, S_sB, S_pB, qwb, qb0b);

    for (int t = 0; t < CITERS; t++) {
        dotsv_kernel<<<gridBN, blk, 0, stream>>>(KVX, S_pB, S_sB,
            msum[(t + 1) & 1], t > 0 ? 1 : 0, G2b, gb1b,
            qwb, qb0b, nullptr, Wacc, msum[t & 1]);
        rowgemmG_kernel<<<dim3(CBS, 3*CD/128, 2), dim3(128), 0, stream>>>(
            Wacc, Pg, bgv, giRaw, slots, gru_whh, gru_bhh, ghRaw, msum[t & 1], 3 * CD, CD);
        gate_mlp1_kernel<<<dim3(CBS, 8), dim3(128), 0, stream>>>(giRaw, ghRaw, slots,
            mlp_ln_g, mlp_ln_b, mlp_w1, mlp_b1, mlp_w2, snewb, slotsAcc,
            Wacc, msum[(t + 1) & 1]);
        slotsup_kernel<<<CBS, blk, 0, stream>>>(slotsAcc, mlp_b2, snewb,
            ln_g, ln_b, wqbb, Pq, slots, qwb, qb0b);
    }
    // final: write attn (+ msum for its m0), then fused scale + out GEMV
    dotsv_kernel<<<gridBN, blk, 0, stream>>>(KVX, S_pB, S_sB,
        msum[0], 1, G2b, gb1b, qwb, qb0b, attnb, nullptr, msum[1]);
    final_kernel<<<dim3(CBS, 3), dim3(128), 0, stream>>>(slots, fin_w, fin_b,
        out0, attnb, msum[1]);
}

// Round 15
// 554.531 us; speedup vs baseline: 1.0258x; 1.0002x over previous
//
#include <hip/hip_runtime.h>

// ---------------- problem constants ----------------
constexpr int CB   = 8;      // batch
constexpr int CN   = 1369;   // tokens (37*37)
constexpr int CDIN = 768;
constexpr int CS   = 7;      // slots
constexpr int CD   = 256;
constexpr int CITERS = 3;
constexpr int CRES = 37;
constexpr float CSIGMA = 5.0f;
constexpr int CBS = CB * CS;        // 56
constexpr int CBN = CB * CN;        // 10952 rows for initial mlp
constexpr int CKV = 2 * CD;         // interleaved KX|VX row stride
constexpr float LNEPS = 1e-5f;
constexpr float ATTN_EPS = 1e-8f;

typedef unsigned short u16;
typedef short bs8 __attribute__((ext_vector_type(8)));   // 8 bf16 (bit pattern in shorts)
typedef float f4 __attribute__((ext_vector_type(4)));

// ---------------- helpers ----------------
__device__ __forceinline__ float ag_x(int n) { return -1.f + (float)(n % CRES) * (2.f / 36.f); }
__device__ __forceinline__ float ag_y(int n) { return -1.f + (float)(n / CRES) * (2.f / 36.f); }

__device__ __forceinline__ u16 bf_rne(float f) {
    unsigned u = __float_as_uint(f);
    return (u16)((u + 0x7FFFu + ((u >> 16) & 1u)) >> 16);
}
__device__ __forceinline__ float bf_to_f(u16 h) { return __uint_as_float(((unsigned)h) << 16); }

__device__ __forceinline__ void split2b(float v, u16& h, u16& m) {
    h = bf_rne(v);
    m = bf_rne(v - bf_to_f(h));
}

// async global->LDS, 16B per lane (dest = wave-uniform base + lane*16)
__device__ __forceinline__ void async16(const u16* g, u16* l) {
    __builtin_amdgcn_global_load_lds(
        (const __attribute__((address_space(1))) unsigned int*)g,
        (__attribute__((address_space(3))) unsigned int*)l, 16, 0, 0);
}

// 256-thread block sum (3 barriers)
__device__ __forceinline__ float block_reduce_sum(float v, float* sbuf) {
    #pragma unroll
    for (int off = 32; off > 0; off >>= 1) v += __shfl_down(v, off, 64);
    if ((threadIdx.x & 63) == 0) sbuf[threadIdx.x >> 6] = v;
    __syncthreads();
    if (threadIdx.x == 0) sbuf[0] = sbuf[0] + sbuf[1] + sbuf[2] + sbuf[3];
    __syncthreads();
    float r = sbuf[0];
    __syncthreads();
    return r;
}

// 256-thread joint (sum, sumsq) reduction (2 barriers). r0 keeps the same
// wave-partial summation order as block_reduce_sum.
__device__ __forceinline__ void block_reduce_sum2(float v0, float v1, float* sbuf,
        float& r0, float& r1) {
    #pragma unroll
    for (int off = 32; off > 0; off >>= 1) {
        v0 += __shfl_down(v0, off, 64);
        v1 += __shfl_down(v1, off, 64);
    }
    if ((threadIdx.x & 63) == 0) {
        sbuf[(threadIdx.x >> 6) * 2]     = v0;
        sbuf[(threadIdx.x >> 6) * 2 + 1] = v1;
    }
    __syncthreads();
    r0 = ((sbuf[0] + sbuf[2]) + sbuf[4]) + sbuf[6];
    r1 = ((sbuf[1] + sbuf[3]) + sbuf[5]) + sbuf[7];
    __syncthreads();
}

// 128-thread joint (sum, sumsq) reduction (2 barriers)
__device__ __forceinline__ void block_reduce_sum2_128(float v0, float v1, float* sbuf,
        float& r0, float& r1) {
    #pragma unroll
    for (int off = 32; off > 0; off >>= 1) {
        v0 += __shfl_down(v0, off, 64);
        v1 += __shfl_down(v1, off, 64);
    }
    if ((threadIdx.x & 63) == 0) {
        sbuf[(threadIdx.x >> 6) * 2]     = v0;
        sbuf[(threadIdx.x >> 6) * 2 + 1] = v1;
    }
    __syncthreads();
    r0 = sbuf[0] + sbuf[2];
    r1 = sbuf[1] + sbuf[3];
    __syncthreads();
}

// ---------------- layernorm (d=256) -> split-2 bf16 planes, joint reduction ----------------
__global__ __launch_bounds__(256) void ln_planes256_kernel(const float* __restrict__ in,
        u16* __restrict__ Yh, u16* __restrict__ Ym,
        const float* __restrict__ g, const float* __restrict__ b) {
    __shared__ float sbuf[8];
    int row = blockIdx.x, t = threadIdx.x;
    float x = in[(size_t)row * CD + t];
    float s, sq;
    block_reduce_sum2(x, x * x, sbuf, s, sq);
    float mean = s / CD;
    float var = fmaxf(sq / CD - mean * mean, 0.f);
    float rstd = rsqrtf(var + LNEPS);
    float y = (x - mean) * rstd * g[t] + b[t];
    u16 h, m; split2b(y, h, m);
    Yh[(size_t)row * CD + t] = h; Ym[(size_t)row * CD + t] = m;
}

// ---------------- mega prep: ln_planes(inputs,768) + transposes + wprep + accZero ----------------
__global__ __launch_bounds__(256) void mega_prep_kernel(
        const float* __restrict__ inputs, u16* __restrict__ xlnh, u16* __restrict__ xlnm,
        const float* __restrict__ im_ln1_g, const float* __restrict__ im_ln1_b,
        const float* __restrict__ im_w1, u16* __restrict__ w1th, u16* __restrict__ w1tm,
        const float* __restrict__ im_w2, u16* __restrict__ w2th, u16* __restrict__ w2tm,
        const float* __restrict__ Wk, const float* __restrict__ Wv,
        const float* __restrict__ Wq,
        const float* __restrict__ f_w1, const float* __restrict__ f_w2,
        u16* __restrict__ kvth, u16* __restrict__ kvtm, float* __restrict__ Pq,
        const float* __restrict__ wih, float* __restrict__ Pg,
        const float* __restrict__ g_w, const float* __restrict__ g_b,
        const float* __restrict__ f_b1,
        float* __restrict__ G2, float* __restrict__ gb1,
        const float* __restrict__ f_b2, const float* __restrict__ bih,
        float* __restrict__ bg, float* __restrict__ wqb,
        float* __restrict__ accZ, int accN) {
    __shared__ float shm[1056];        // union: sbuf[8] | tile[32][33] | arow[256]
    int bid = blockIdx.x;
    int t = threadIdx.x;
    if (bid < CBN) {
        // ---- ln_planes d=768 (joint reduction) ----
        int row = bid;
        const float* x = inputs + (size_t)row * CDIN;
        float v0 = x[t], v1 = x[t + 256], v2 = x[t + 512];
        float s, sq;
        block_reduce_sum2(v0 + v1 + v2, v0 * v0 + v1 * v1 + v2 * v2, shm, s, sq);
        float mean = s / CDIN;
        float var = fmaxf(sq / CDIN - mean * mean, 0.f);
        float rstd = rsqrtf(var + LNEPS);
        u16 h, m;
        float y = (v0 - mean) * rstd * im_ln1_g[t] + im_ln1_b[t];
        split2b(y, h, m);
        xlnh[(size_t)row * CDIN + t] = h; xlnm[(size_t)row * CDIN + t] = m;
        float y1 = (v1 - mean) * rstd * im_ln1_g[t + 256] + im_ln1_b[t + 256];
        split2b(y1, h, m);
        xlnh[(size_t)row * CDIN + t + 256] = h; xlnm[(size_t)row * CDIN + t + 256] = m;
        float y2 = (v2 - mean) * rstd * im_ln1_g[t + 512] + im_ln1_b[t + 512];
        split2b(y2, h, m);
        xlnh[(size_t)row * CDIN + t + 512] = h; xlnm[(size_t)row * CDIN + t + 512] = m;
        return;
    }
    if (bid < CBN + 768) {
        // ---- transpose_split2 ----
        int tb = bid - CBN;
        const float* W; u16 *Th, *Tm; int N, bx, by;
        if (tb < 576) { W = im_w1; Th = w1th; Tm = w1tm; N = CDIN; bx = tb % 24; by = tb / 24; }
        else { tb -= 576; W = im_w2; Th = w2th; Tm = w2tm; N = CD; bx = tb % 8; by = tb / 8; }
        int K = CDIN;
        float (*tile)[33] = (float(*)[33])shm;
        int nb = bx * 32, kb = by * 32;
        int tx = t & 31, ty = t >> 5;
        #pragma unroll
        for (int i = 0; i < 32; i += 8)
            tile[ty + i][tx] = W[(size_t)(kb + ty + i) * N + nb + tx];
        __syncthreads();
        #pragma unroll
        for (int i = 0; i < 32; i += 8) {
            float v = tile[tx][ty + i];
            u16 h, m; split2b(v, h, m);
            size_t idx = (size_t)(nb + ty + i) * K + kb + tx;
            Th[idx] = h; Tm[idx] = m;
        }
        return;
    }
    if (bid >= CBN + 768 + 1541) {
        // ---- zero accumulators ----
        int zb = bid - (CBN + 768 + 1541);
        int fi = (zb * 256 + t) * 4;
        if (fi + 3 < accN) *(f4*)(accZ + fi) = (f4){0.f, 0.f, 0.f, 0.f};
        else for (int i = fi; i < accN; i++) accZ[i] = 0.f;
        return;
    }
    // ---- wprep ----
    int wb = bid - CBN - 768;
    float* arow = shm;
    int n = t;
    if (wb < 512) {
        const float* A = (wb < 256) ? Wk : Wv;
        int k = wb & 255;
        size_t poff = (wb < 256) ? 0 : (size_t)CD * CD;
        arow[n] = A[k * CD + n];
        __syncthreads();
        float acc = 0.f;
        for (int j = 0; j < CD; j++) acc += arow[j] * f_w1[(size_t)j * CD + n];
        u16 h, m; split2b(acc, h, m);
        kvth[poff + (size_t)n * CD + k] = h;
        kvtm[poff + (size_t)n * CD + k] = m;
    } else if (wb < 768) {
        int k = wb - 512;
        arow[n] = Wq[k * CD + n];
        __syncthreads();
        float acc = 0.f;
        for (int c = 0; c < CD; c++) acc += arow[c] * f_w2[(size_t)n * CD + c];
        Pq[(size_t)k * CD + n] = acc;
    } else if (wb < 1536) {
        int wb2 = wb - 768;
        int k = wb2 & 255;
        int ny = wb2 >> 8;
        arow[n] = f_w2[k * CD + n];
        __syncthreads();
        int nn = ny * 256 + n;
        float acc = 0.f;
        for (int j = 0; j < CD; j++) acc += arow[j] * wih[(size_t)j * (3 * CD) + nn];
        Pg[(size_t)k * (3 * CD) + nn] = acc;
    } else if (wb == 1536) {
        float a0 = 0.f, a1 = 0.f, ab = 0.f;
        for (int j = 0; j < CD; j++) {
            float w = f_w1[j * CD + n];
            a0 += g_w[j] * w;
            a1 += g_w[CD + j] * w;
            ab += g_b[j] * w;
        }
        G2[n] = a0; G2[CD + n] = a1; gb1[n] = ab + f_b1[n];
    } else if (wb <= 1539) {
        int nn = (wb - 1537) * 256 + n;
        float s = bih[nn];
        for (int c = 0; c < CD; c++) s += f_b2[c] * wih[(size_t)c * (3 * CD) + nn];
        bg[nn] = s;
    } else {
        float s = 0.f;
        for (int c = 0; c < CD; c++) s += Wq[n * CD + c] * f_b2[c];
        wqb[n] = s;
    }
}

// ---------------- bf16x3 plane GEMM, BM=64 x BN, NBUF-deep counted-vmcnt pipeline ----------------
// #1: BN=128, NBUF=2 (proven ~68-70us). #2: BN=64, NBUF=3. #3: BN=128, NBUF=2.
// LDS slot swizzle via inverse-permuted global source; bijective XCD swizzle.
// NOTE: SQ_LDS_BANK_CONFLICT ~= 8 cyc per global_load_lds wave-issue is the
// structural LDS-write transfer time (1024B / 128B-per-cyc), not fixable.
template<int BN, int NBUF>
__global__ __launch_bounds__(256)
void hgemm2(const u16* __restrict__ Ah, const u16* __restrict__ Am,
            const u16* __restrict__ Bh, const u16* __restrict__ Bm,
            int M, int N, int K, const float* __restrict__ bias, int relu,
            float* __restrict__ Cf, u16* __restrict__ Ch, u16* __restrict__ Cm) {
    constexpr int BP = BN * 32;            // u16 per B plane
    constexpr int SB = 4096 + 2 * BP;      // u16 per LDS buffer
    constexpr int NI = 2 + 2 * (BN / 64);  // staging issues per k-step: 6 or 4
    constexpr int NF = BN / 32;            // B frags per wave: 4 or 2
    constexpr int PP = BN / 64;            // issues per B plane: 2 or 1
    __shared__ u16 smem[NBUF][SB];
    const int tid = threadIdx.x;

    int bx = blockIdx.x, by = blockIdx.y;
    {
        int gx = gridDim.x;
        int nwg = gx * gridDim.y;
        if (!(nwg & 7)) {               // XCD-aware swizzle (bijective, nwg%8==0)
            int bid = by * gx + bx;
            int cpx = nwg >> 3;
            int s = (bid & 7) * cpx + (bid >> 3);
            bx = s % gx; by = s / gx;
        }
    }
    const int m0 = by * 64, n0 = bx * BN;
    const int w = tid >> 6, lane = tid & 63;
    const int wm = w & 1, wn = w >> 1;
    const int l15 = lane & 15, l4 = lane >> 4;

    // staging map: i0=Ah, i1=Am, then B planes (PP issues each)
    const u16* srcp[NI];
    int dsto[NI];
    #pragma unroll
    for (int i = 0; i < NI; i++) {
        const u16* bp; int row, r, c;
        if (i < 2) {                       // A planes: 64 rows x 4 chunks = 256
            int qq = tid;
            r = qq >> 2;
            c = (qq & 3) ^ ((r ^ (r >> 2)) & 3);   // inverse swizzle on source
            bp = (i == 0) ? Ah : Am;
            row = m0 + r; row = row < M ? row : M - 1;
            dsto[i] = i * 2048 + w * 512;
        } else {                           // B planes: BN rows x 4 chunks
            int ii = i - 2;
            int plane = ii / PP;           // 0:Bh 1:Bm
            int sub = ii % PP;
            int qq = sub * 256 + tid;
            r = qq >> 2;
            c = (qq & 3) ^ ((r ^ (r >> 2)) & 3);
            bp = plane ? Bm : Bh;
            row = n0 + r;
            dsto[i] = 4096 + plane * BP + sub * 2048 + w * 512;
        }
        srcp[i] = bp + (size_t)row * K + c * 8;
    }

    f4 acc[2][NF];
    #pragma unroll
    for (int i = 0; i < 2; i++)
        #pragma unroll
        for (int j = 0; j < NF; j++) acc[i][j] = (f4){0.f, 0.f, 0.f, 0.f};

    // swizzled k-chunk slot for fragment reads
    const int cx8 = (l4 ^ (l15 & 3) ^ ((l15 >> 2) & 3)) * 8;

    const int ns = K / 32;
    // prologue: stage steps 0..D-1 (no drain)
    #pragma unroll
    for (int d = 0; d < NBUF - 1; d++)
        #pragma unroll
        for (int i = 0; i < NI; i++) async16(srcp[i] + d * 32, &smem[d][dsto[i]]);

    u16* c0 = &smem[0][0];
    u16* c1 = &smem[NBUF > 1 ? 1 : 0][0];
    u16* c2 = &smem[NBUF - 1][0];

    for (int k = 0; k < ns; k++) {
        if constexpr (NBUF == 3) {
            if (k + 2 < ns) {
                #pragma unroll
                for (int i = 0; i < NI; i++) async16(srcp[i] + (k + 2) * 32, c2 + dsto[i]);
                if constexpr (BN == 64) asm volatile("s_waitcnt vmcnt(8)" ::: "memory");
                else                     asm volatile("s_waitcnt vmcnt(12)" ::: "memory");
            } else if (k + 1 < ns) {
                if constexpr (BN == 64) asm volatile("s_waitcnt vmcnt(4)" ::: "memory");
                else                     asm volatile("s_waitcnt vmcnt(6)" ::: "memory");
            } else {
                asm volatile("s_waitcnt vmcnt(0)" ::: "memory");
            }
        } else {
            if (k + 1 < ns) {
                #pragma unroll
                for (int i = 0; i < NI; i++) async16(srcp[i] + (k + 1) * 32, c1 + dsto[i]);
                if constexpr (BN == 64) asm volatile("s_waitcnt vmcnt(4)" ::: "memory");
                else                     asm volatile("s_waitcnt vmcnt(6)" ::: "memory");
            } else {
                asm volatile("s_waitcnt vmcnt(0)" ::: "memory");
            }
        }
        __builtin_amdgcn_s_barrier();        // all threads' step-k loads landed
        bs8 ah[2], am[2], bh[NF], bm[NF];
        #pragma unroll
        for (int f = 0; f < 2; f++) {
            int oa = (wm * 32 + f * 16 + l15) * 32 + cx8;
            ah[f] = *(const bs8*)(c0 + oa);
            am[f] = *(const bs8*)(c0 + 2048 + oa);
        }
        #pragma unroll
        for (int f = 0; f < NF; f++) {
            int ob = (wn * (NF * 16) + f * 16 + l15) * 32 + cx8;
            bh[f] = *(const bs8*)(c0 + 4096 + ob);
            bm[f] = *(const bs8*)(c0 + 4096 + BP + ob);
        }
        #pragma unroll
        for (int mf = 0; mf < 2; mf++)
            #pragma unroll
            for (int nf = 0; nf < NF; nf++) {
                acc[mf][nf] = __builtin_amdgcn_mfma_f32_16x16x32_bf16(am[mf], bh[nf], acc[mf][nf], 0, 0, 0);
                acc[mf][nf] = __builtin_amdgcn_mfma_f32_16x16x32_bf16(ah[mf], bm[nf], acc[mf][nf], 0, 0, 0);
                acc[mf][nf] = __builtin_amdgcn_mfma_f32_16x16x32_bf16(ah[mf], bh[nf], acc[mf][nf], 0, 0, 0);
            }
        asm volatile("" ::: "memory");       // keep LDS reads ordered vs barrier
        __builtin_amdgcn_s_barrier();        // all done reading c0 (no vmcnt drain!)
        if constexpr (NBUF == 3) { u16* t_ = c0; c0 = c1; c1 = c2; c2 = t_; }
        else                     { u16* t_ = c0; c0 = c1; c1 = t_; }
    }

    #pragma unroll
    for (int mf = 0; mf < 2; mf++)
        #pragma unroll
        for (int i = 0; i < 4; i++) {
            int grow = m0 + wm * 32 + mf * 16 + l4 * 4 + i;
            if (grow < M) {
                #pragma unroll
                for (int nf = 0; nf < NF; nf++) {
                    int col = n0 + wn * (NF * 16) + nf * 16 + l15;
                    float v = acc[mf][nf][i] + (bias ? bias[col] : 0.f);
                    if (relu) v = fmaxf(v, 0.f);
                    if (Cf) Cf[(size_t)grow * N + col] = v;
                    else {
                        u16 h, m; split2b(v, h, m);
                        Ch[(size_t)grow * N + col] = h;
                        Cm[(size_t)grow * N + col] = m;
                    }
                }
            }
        }
}

// gi/gh pair in one launch via blockIdx.z; z==0 rows scaled by 1/m0 (from msum)
__global__ __launch_bounds__(128) void rowgemmG_kernel(
        const float* __restrict__ A0, const float* __restrict__ W0,
        const float* __restrict__ b0, float* __restrict__ C0,
        const float* __restrict__ A1, const float* __restrict__ W1,
        const float* __restrict__ b1, float* __restrict__ C1,
        const float* __restrict__ msum, int N, int K) {
    __shared__ float sA[256];
    const float* A = blockIdx.z ? A1 : A0;
    const float* W = blockIdx.z ? W1 : W0;
    const float* B = blockIdx.z ? b1 : b0;
    float* C = blockIdx.z ? C1 : C0;
    int r = blockIdx.x;
    int c = blockIdx.y * 128 + threadIdx.x;
    float scl = blockIdx.z ? 1.f : 1.f / msum[r * 8];
    for (int i = threadIdx.x; i < K; i += 128) sA[i] = A[(size_t)r * K + i] * scl;
    __syncthreads();
    float a0 = 0.f, a1 = 0.f, a2 = 0.f, a3 = 0.f;
    #pragma unroll 4
    for (int k = 0; k < K; k += 4) {
        a0 += sA[k]     * W[(size_t)k * N + c];
        a1 += sA[k + 1] * W[(size_t)(k + 1) * N + c];
        a2 += sA[k + 2] * W[(size_t)(k + 2) * N + c];
        a3 += sA[k + 3] * W[(size_t)(k + 3) * N + c];
    }
    C[(size_t)r * N + c] = (a0 + a1) + (a2 + a3) + B[c];
}

// ---------------- fused init: slots broadcast + S init + LN + qb0 + qw (t=0) ----------------
__global__ __launch_bounds__(256) void init_ln_q_kernel(const float* __restrict__ slots_init_p,
        const float* __restrict__ S_s0, const float* __restrict__ S_p0,
        const float* __restrict__ ln_g, const float* __restrict__ ln_b,
        const float* __restrict__ wqb, const float* __restrict__ Pq,
        float* __restrict__ slots, float* __restrict__ S_s, float* __restrict__ S_p,
        float* __restrict__ qwb, float* __restrict__ qb0) {
    __shared__ float sbuf[8];
    __shared__ float sN[CD];
    int row = blockIdx.x, t = threadIdx.x;
    int s = row % CS;
    float x = slots_init_p[s * CD + t];
    slots[row * CD + t] = x;
    if (t < 2) { S_s[row * 2 + t] = S_s0[s * 2 + t]; S_p[row * 2 + t] = S_p0[s * 2 + t]; }
    float sm, sq;
    block_reduce_sum2(x, x * x, sbuf, sm, sq);
    float mean = sm / CD;
    float var = fmaxf(sq / CD - mean * mean, 0.f);
    float sn = (x - mean) * rsqrtf(var + LNEPS) * ln_g[t] + ln_b[t];
    sN[t] = sn;
    float qb = block_reduce_sum(sn * wqb[t], sbuf);
    if (t == 0) qb0[row] = qb;
    __syncthreads();
    float acc = 0.f;
    #pragma unroll 4
    for (int k = 0; k < CD; k++) acc += sN[k] * Pq[(size_t)k * CD + t];
    qwb[row * CD + t] = acc;
}

// fused slots finalize: slots = snew + b2 + slotsAcc (w2 GEMV pre-accumulated by
// gate_mlp1 via atomics); zero slotsAcc for next iter; LN + qb0 + qw GEMV.
__global__ __launch_bounds__(256) void slotsup_kernel(float* __restrict__ slotsAcc,
        const float* __restrict__ b2, const float* __restrict__ snewb,
        const float* __restrict__ ln_g, const float* __restrict__ ln_b,
        const float* __restrict__ wqb, const float* __restrict__ Pq,
        float* __restrict__ slots, float* __restrict__ qwb, float* __restrict__ qb0) {
    __shared__ float sbuf[8];
    __shared__ float sN[CD];
    int row = blockIdx.x, t = threadIdx.x;
    float v = snewb[row * CD + t] + b2[t] + slotsAcc[row * CD + t];
    slotsAcc[row * CD + t] = 0.f;          // ready for next iteration's atomics
    slots[row * CD + t] = v;
    float sm, sq;
    block_reduce_sum2(v, v * v, sbuf, sm, sq);
    float mean = sm / CD;
    float var = fmaxf(sq / CD - mean * mean, 0.f);
    float sn = (v - mean) * rsqrtf(var + LNEPS) * ln_g[t] + ln_b[t];
    sN[t] = sn;
    float qb = block_reduce_sum(sn * wqb[t], sbuf);
    if (t == 0) qb0[row] = qb;
    __syncthreads();
    float acc = 0.f;
    #pragma unroll 4
    for (int k = 0; k < CD; k++) acc += sN[k] * Pq[(size_t)k * CD + t];
    qwb[row * CD + t] = acc;
}

// dots + softmax-over-slots + (optional) vsum + (optional) fused moments.
// Moments are lane-distributed: lanes 0-34 each own one (slot, moment) pair.
// Wacc block-reduce stages ALL 7 slots in LDS at once (28KB): 15 barriers -> 3.
// Per-(s,c) summation order (w0+w1+w2+w3, then atomic) unchanged -> bit-identical.
__global__ __launch_bounds__(256) void dotsv_kernel(const float* __restrict__ KVX,
        const float* __restrict__ S_p, const float* __restrict__ S_s,
        const float* __restrict__ msum_in, int useMsum,
        const float* __restrict__ G2, const float* __restrict__ gb1,
        const float* __restrict__ qw, const float* __restrict__ qb0,
        float* __restrict__ attn, float* __restrict__ Wacc,
        float* __restrict__ msum_out) {
    __shared__ float sred[CS * 4 * CD];    // 7 x 4 waves x 256 ch = 28 KB
    int b = blockIdx.x;
    int w = threadIdx.x >> 6, l = threadIdx.x & 63;
    int k4 = l * 4;
    float4 g0 = *(const float4*)(G2 + k4);
    float4 g1 = *(const float4*)(G2 + CD + k4);
    float4 gb = *(const float4*)(gb1 + k4);
    float4 qwv[CS]; float px[CS], py[CS], ix[CS], iy[CS], q0[CS];
    #pragma unroll
    for (int s = 0; s < CS; s++) {
        int bs = b * CS + s;
        qwv[s] = *(const float4*)(qw + bs * CD + k4);
        if (useMsum) {
            const float* mp = msum_in + bs * 8;
            float m0 = mp[0];
            float pxv = mp[1] / m0, pyv = mp[2] / m0;
            float sx = sqrtf(fmaxf(mp[3] / m0 - pxv * pxv, 0.f));
            float sy = sqrtf(fmaxf(mp[4] / m0 - pyv * pyv, 0.f));
            px[s] = pxv; py[s] = pyv;
            ix[s] = 1.f / (sx * CSIGMA); iy[s] = 1.f / (sy * CSIGMA);
        } else {
            px[s] = S_p[2 * bs]; py[s] = S_p[2 * bs + 1];
            ix[s] = 1.f / (S_s[2 * bs] * CSIGMA); iy[s] = 1.f / (S_s[2 * bs + 1] * CSIGMA);
        }
        q0[s] = qb0[bs];
    }
    float4 acc[CS];
    #pragma unroll
    for (int s = 0; s < CS; s++) acc[s] = make_float4(0.f, 0.f, 0.f, 0.f);
    float wmv = 0.f;
    int sidx = l / 5;
    int jidx = l - sidx * 5;
    int nbase = blockIdx.y * 16 + w * 4;
    #pragma unroll
    for (int i = 0; i < 4; i++) {
        int n = nbase + i;
        int nc = n < CN ? n : CN - 1;
        const float* rowp = KVX + (size_t)(b * CN + nc) * CKV;
        float4 kx = *(const float4*)(rowp + k4);
        float ax = ag_x(nc), ay = ag_y(nc);
        float dsv[CS];
        #pragma unroll
        for (int s = 0; s < CS; s++) {
            float r0 = (ax - px[s]) * ix[s];
            float r1 = (ay - py[s]) * iy[s];
            float v0 = fmaxf(kx.x + r0 * g0.x + r1 * g1.x + gb.x, 0.f);
            float v1 = fmaxf(kx.y + r0 * g0.y + r1 * g1.y + gb.y, 0.f);
            float v2 = fmaxf(kx.z + r0 * g0.z + r1 * g1.z + gb.z, 0.f);
            float v3 = fmaxf(kx.w + r0 * g0.w + r1 * g1.w + gb.w, 0.f);
            float d = v0 * qwv[s].x + v1 * qwv[s].y + v2 * qwv[s].z + v3 * qwv[s].w;
            #pragma unroll
            for (int off = 32; off > 0; off >>= 1) d += __shfl_xor(d, off, 64);
            dsv[s] = 0.0625f * (d + q0[s]);
        }
        float mx = -1e30f;
        #pragma unroll
        for (int s = 0; s < CS; s++) mx = fmaxf(mx, dsv[s]);
        float sum = 0.f;
        #pragma unroll
        for (int s = 0; s < CS; s++) { dsv[s] = __expf(dsv[s] - mx); sum += dsv[s]; }
        float inv = 1.f / sum;
        #pragma unroll
        for (int s = 0; s < CS; s++) dsv[s] = dsv[s] * inv + ATTN_EPS;
        if (attn && l == 0 && n < CN) {
            #pragma unroll
            for (int s = 0; s < CS; s++)
                attn[(size_t)(b * CS + s) * CN + n] = dsv[s];
        }
        if (msum_out && n < CN) {
            float ax2 = ax * ax, ay2 = ay * ay;
            float a = dsv[0];
            a = (sidx == 1) ? dsv[1] : a;
            a = (sidx == 2) ? dsv[2] : a;
            a = (sidx == 3) ? dsv[3] : a;
            a = (sidx == 4) ? dsv[4] : a;
            a = (sidx == 5) ? dsv[5] : a;
            a = (sidx == 6) ? dsv[6] : a;
            float coef = 1.f;
            coef = (jidx == 1) ? ax : coef;
            coef = (jidx == 2) ? ay : coef;
            coef = (jidx == 3) ? ax2 : coef;
            coef = (jidx == 4) ? ay2 : coef;
            wmv += a * coef;
        }
        if (Wacc && n < CN) {
            float4 vx = *(const float4*)(rowp + CD + k4);
            #pragma unroll
            for (int s = 0; s < CS; s++) {
                float r0 = (ax - px[s]) * ix[s];
                float r1 = (ay - py[s]) * iy[s];
                float a = dsv[s];
                acc[s].x += a * fmaxf(vx.x + r0 * g0.x + r1 * g1.x + gb.x, 0.f);
                acc[s].y += a * fmaxf(vx.y + r0 * g0.y + r1 * g1.y + gb.y, 0.f);
                acc[s].z += a * fmaxf(vx.z + r0 * g0.z + r1 * g1.z + gb.z, 0.f);
                acc[s].w += a * fmaxf(vx.w + r0 * g0.w + r1 * g1.w + gb.w, 0.f);
            }
        }
    }
    if (Wacc) {
        // stage all 7 slots at once; one barrier; per-thread 4-wave sum + atomic
        #pragma unroll
        for (int s = 0; s < CS; s++)
            ((f4*)sred)[s * 256 + w * 64 + l] = *(f4*)&acc[s];
        __syncthreads();
        #pragma unroll
        for (int s = 0; s < CS; s++) {
            const float* sp = sred + s * 1024;
            float v = sp[threadIdx.x] + sp[CD + threadIdx.x]
                    + sp[2 * CD + threadIdx.x] + sp[3 * CD + threadIdx.x];
            atomicAdd(&Wacc[(size_t)(b * CS + s) * CD + threadIdx.x], v);
        }
        __syncthreads();
    }
    if (msum_out) {
        if (l < 35) sred[w * 35 + l] = wmv;
        __syncthreads();
        if (threadIdx.x < 35) {
            float v = sred[threadIdx.x] + sred[35 + threadIdx.x]
                    + sred[70 + threadIdx.x] + sred[105 + threadIdx.x];
            int s = threadIdx.x / 5, j = threadIdx.x % 5;
            atomicAdd(&msum_out[(size_t)(b * CS + s) * 8 + j], v);
        }
    }
}

// fused GRU gate + LN + h1 GEMV + partial slots GEMV (h1 @ w2 accumulated into
// slotsAcc via atomics). Grid (CBS, 8) x 128 threads; h1 never hits memory.
__global__ __launch_bounds__(128) void gate_mlp1_kernel(const float* __restrict__ giRaw,
        const float* __restrict__ ghRaw, const float* __restrict__ slots,
        const float* __restrict__ mg, const float* __restrict__ mb,
        const float* __restrict__ mlp_w1, const float* __restrict__ mlp_b1,
        const float* __restrict__ w2,
        float* __restrict__ snewb, float* __restrict__ slotsAcc,
        float* __restrict__ WaccZ, float* __restrict__ msumZ) {
    __shared__ float sbuf[4];
    __shared__ float sM[CD];
    __shared__ float sH1[128];
    int row = blockIdx.x, t = threadIdx.x;
    float snew[2];
    #pragma unroll
    for (int e = 0; e < 2; e++) {
        int tt = t + e * 128;
        float gi0 = giRaw[row * 3 * CD + tt];
        float gi1 = giRaw[row * 3 * CD + CD + tt];
        float gi2 = giRaw[row * 3 * CD + 2 * CD + tt];
        float gh0 = ghRaw[row * 3 * CD + tt];
        float gh1 = ghRaw[row * 3 * CD + CD + tt];
        float gh2 = ghRaw[row * 3 * CD + 2 * CD + tt];
        float r = 1.f / (1.f + expf(-(gi0 + gh0)));
        float z = 1.f / (1.f + expf(-(gi1 + gh1)));
        float nn = tanhf(gi2 + r * gh2);
        snew[e] = (1.f - z) * nn + z * slots[row * CD + tt];
    }
    if (blockIdx.y == 0) {
        snewb[row * CD + t] = snew[0];
        snewb[row * CD + t + 128] = snew[1];
        WaccZ[row * CD + t] = 0.f;
        WaccZ[row * CD + t + 128] = 0.f;
        if (t < 8) msumZ[row * 8 + t] = 0.f;
    }
    float sm, sq;
    block_reduce_sum2_128(snew[0] + snew[1],
        snew[0] * snew[0] + snew[1] * snew[1], sbuf, sm, sq);
    float mean = sm / CD;
    float var = fmaxf(sq / CD - mean * mean, 0.f);
    float rstd = rsqrtf(var + LNEPS);
    sM[t]       = (snew[0] - mean) * rstd * mg[t] + mb[t];
    sM[t + 128] = (snew[1] - mean) * rstd * mg[t + 128] + mb[t + 128];
    __syncthreads();
    int c = blockIdx.y * 128 + t;
    float a0 = 0.f, a1 = 0.f, a2 = 0.f, a3 = 0.f;
    #pragma unroll 4
    for (int k = 0; k < CD; k += 4) {
        a0 += sM[k]     * mlp_w1[(size_t)k * (4 * CD) + c];
        a1 += sM[k + 1] * mlp_w1[(size_t)(k + 1) * (4 * CD) + c];
        a2 += sM[k + 2] * mlp_w1[(size_t)(k + 2) * (4 * CD) + c];
        a3 += sM[k + 3] * mlp_w1[(size_t)(k + 3) * (4 * CD) + c];
    }
    sH1[t] = fmaxf((a0 + a1) + (a2 + a3) + mlp_b1[c], 0.f);
    __syncthreads();
    // partial slots GEMV over this block's 128 h1 values (k = by*128 + cc)
    float p0 = 0.f, p1 = 0.f;
    const float* w2b = w2 + (size_t)blockIdx.y * 128 * CD;
    #pragma unroll 4
    for (int cc = 0; cc < 128; cc++) {
        float h = sH1[cc];
        p0 += h * w2b[(size_t)cc * CD + t];
        p1 += h * w2b[(size_t)cc * CD + t + 128];
    }
    atomicAdd(&slotsAcc[row * CD + t], p0);
    atomicAdd(&slotsAcc[row * CD + t + 128], p1);
}

// fused final: by<2 -> out0 = slots @ fin_w + fin_b (128 cols each);
// by==2 -> attn row scale by 1/m0.
__global__ __launch_bounds__(128) void final_kernel(const float* __restrict__ slots,
        const float* __restrict__ fin_w, const float* __restrict__ fin_b,
        float* __restrict__ out0, float* __restrict__ attn,
        const float* __restrict__ msum) {
    int row = blockIdx.x;
    if (blockIdx.y == 2) {
        float inv = 1.f / msum[(size_t)row * 8];
        float* up = attn + (size_t)row * CN;
        for (int n = threadIdx.x; n < CN; n += 128) up[n] *= inv;
        return;
    }
    __shared__ float sA[CD];
    for (int i = threadIdx.x; i < CD; i += 128) sA[i] = slots[(size_t)row * CD + i];
    __syncthreads();
    int c = blockIdx.y * 128 + threadIdx.x;
    float a0 = 0.f, a1 = 0.f, a2 = 0.f, a3 = 0.f;
    #pragma unroll 4
    for (int k = 0; k < CD; k += 4) {
        a0 += sA[k]     * fin_w[(size_t)k * CD + c];
        a1 += sA[k + 1] * fin_w[(size_t)(k + 1) * CD + c];
        a2 += sA[k + 2] * fin_w[(size_t)(k + 2) * CD + c];
        a3 += sA[k + 3] * fin_w[(size_t)(k + 3) * CD + c];
    }
    out0[(size_t)row * CD + c] = (a0 + a1) + (a2 + a3) + fin_b[c];
}

// ---------------- launcher ----------------
extern "C" void kernel_launch(void* const* d_in, const int* in_sizes, int n_in,
                              void* d_out, int out_size, void* d_ws, size_t ws_size,
                              hipStream_t stream) {
    (void)in_sizes; (void)n_in; (void)out_size;
    const float* inputs       = (const float*)d_in[0];
    const float* slots_init_p = (const float*)d_in[1];
    const float* S_s0         = (const float*)d_in[2];
    const float* S_p0         = (const float*)d_in[3];
    const float* im_ln1_g = (const float*)d_in[4];
    const float* im_ln1_b = (const float*)d_in[5];
    const float* im_w1    = (const float*)d_in[6];
    const float* im_b1    = (const float*)d_in[7];
    const float* im_w2    = (const float*)d_in[8];
    const float* im_b2    = (const float*)d_in[9];
    const float* im_ln2_g = (const float*)d_in[10];
    const float* im_ln2_b = (const float*)d_in[11];
    const float* Wq  = (const float*)d_in[12];
    const float* Wk  = (const float*)d_in[13];
    const float* Wv  = (const float*)d_in[14];
    const float* g_w = (const float*)d_in[15];
    const float* g_b = (const float*)d_in[16];
    const float* f_w1 = (const float*)d_in[17];
    const float* f_b1 = (const float*)d_in[18];
    const float* f_w2 = (const float*)d_in[19];
    const float* f_b2 = (const float*)d_in[20];
    const float* ln_g = (const float*)d_in[21];
    const float* ln_b = (const float*)d_in[22];
    const float* gru_wih = (const float*)d_in[23];
    const float* gru_whh = (const float*)d_in[24];
    const float* gru_bih = (const float*)d_in[25];
    const float* gru_bhh = (const float*)d_in[26];
    const float* mlp_ln_g = (const float*)d_in[27];
    const float* mlp_ln_b = (const float*)d_in[28];
    const float* mlp_w1 = (const float*)d_in[29];
    const float* mlp_b1 = (const float*)d_in[30];
    const float* mlp_w2 = (const float*)d_in[31];
    const float* mlp_b2 = (const float*)d_in[32];
    const float* fin_w = (const float*)d_in[33];
    const float* fin_b = (const float*)d_in[34];

    char* base = (char*)d_ws;
    size_t off = 0;
    auto take = [&](size_t bytes) { void* p = base + off; off += (bytes + 255) & ~(size_t)255; return p; };

    float* R1 = (float*)take((size_t)CBN * CDIN * 4);  // xln planes -> xD | xDn planes
    float* R2 = (float*)take((size_t)CBN * CDIN * 4);  // X1 planes -> KVX
    u16* w1th = (u16*)take((size_t)CDIN * CDIN * 2);
    u16* w1tm = (u16*)take((size_t)CDIN * CDIN * 2);
    u16* w2th = (u16*)take((size_t)CDIN * CD * 2);
    u16* w2tm = (u16*)take((size_t)CDIN * CD * 2);
    u16* kvth = (u16*)take((size_t)CKV * CD * 2);      // [512][256]: PkT | PvT
    u16* kvtm = (u16*)take((size_t)CKV * CD * 2);
    float* G2b  = (float*)take((size_t)2 * CD * 4);
    float* gb1b = (float*)take((size_t)CD * 4);
    float* Pq   = (float*)take((size_t)CD * CD * 4);
    float* Pg   = (float*)take((size_t)CD * 3 * CD * 4);
    float* bgv  = (float*)take((size_t)3 * CD * 4);
    float* wqbb = (float*)take((size_t)CD * 4);
    float* qwb   = (float*)take((size_t)CBS * CD * 4);
    float* qb0b  = (float*)take((size_t)CBS * 4);
    // Wacc | msumA | msumB | slotsAcc contiguous: zeroed inside mega_prep
    const int ACCN = CBS * CD * 2 + 2 * CBS * 8;
    float* Wacc  = (float*)take((size_t)ACCN * 4);
    float* msumA = Wacc + (size_t)CBS * CD;
    float* msumB = msumA + (size_t)CBS * 8;
    float* slotsAcc = msumB + (size_t)CBS * 8;
    float* giRaw = (float*)take((size_t)CBS * 3 * CD * 4);
    float* ghRaw = (float*)take((size_t)CBS * 3 * CD * 4);
    float* snewb = (float*)take((size_t)CBS * CD * 4);
    float* S_pB  = (float*)take((size_t)CBS * 2 * 4);
    float* S_sB  = (float*)take((size_t)CBS * 2 * 4);
    float* slots = (float*)take((size_t)CBS * CD * 4);
    if (ws_size < off) return;

    float* msum[2] = {msumA, msumB};

    // plane/buffer aliasing (lifetimes disjoint):
    u16* xlnh = (u16*)R1;                                  // [CBN][768] planes
    u16* xlnm = xlnh + (size_t)CBN * CDIN;
    u16* X1h  = (u16*)R2;                                  // [CBN][768] planes
    u16* X1m  = X1h + (size_t)CBN * CDIN;
    float* xD = R1;                                        // [CBN][256] fp32 (xln dead)
    u16* xDnh = (u16*)(R1 + (size_t)CBN * CD);             // [CBN][256] planes
    u16* xDnm = xDnh + (size_t)CBN * CD;
    float* KVX = R2;                                       // [CBN][512] fp32 (X1 dead)

    float* out0 = (float*)d_out;            // [CBS,CD]
    float* attnb = out0 + CBS * CD;         // [CBS,CN]

    dim3 blk(256);
    const int gM = (CBN + 63) / 64;         // 172 M-tiles (BM=64)
    dim3 gridBN(CB, 86);                    // 8 x 86 (16 n per block)
    const int ZBLK = (ACCN + 1023) / 1024;  // accumulator-zero blocks

    // ---- fused prep: ln_planes#1 + transposes + wprep + acc-zero in one launch ----
    mega_prep_kernel<<<dim3(CBN + 768 + 1541 + ZBLK), blk, 0, stream>>>(
        inputs, xlnh, xlnm, im_ln1_g, im_ln1_b,
        im_w1, w1th, w1tm, im_w2, w2th, w2tm,
        Wk, Wv, Wq, f_w1, f_w2, kvth, kvtm, Pq,
        gru_wih, Pg, g_w, g_b, f_b1, G2b, gb1b,
        f_b2, gru_bih, bgv, wqbb, Wacc, ACCN);

    // ---- initial mlp ----
    hgemm2<128,2><<<dim3(CDIN/128, gM), blk, 0, stream>>>(xlnh, xlnm, w1th, w1tm,
        CBN, CDIN, CDIN, im_b1, 1, nullptr, X1h, X1m);
    hgemm2<64,3><<<dim3(CD/64, gM), blk, 0, stream>>>(X1h, X1m, w2th, w2tm,
        CBN, CD, CDIN, im_b2, 0, xD, nullptr, nullptr);
    ln_planes256_kernel<<<CBN, blk, 0, stream>>>(xD, xDnh, xDnm, im_ln2_g, im_ln2_b);
    hgemm2<128,2><<<dim3(CKV/128, gM), blk, 0, stream>>>(xDnh, xDnm, kvth, kvtm,
        CBN, CKV, CD, nullptr, 0, KVX, nullptr, nullptr);
    init_ln_q_kernel<<<CBS, blk, 0, stream>>>(slots_init_p, S_s0, S_p0,
        ln_g, ln_b, wqbb, Pq, slots, S_sB, S_pB, qwb, qb0b);

    for (int t = 0; t < CITERS; t++) {
        dotsv_kernel<<<gridBN, blk, 0, stream>>>(KVX, S_pB, S_sB,
            msum[(t + 1) & 1], t > 0 ? 1 : 0, G2b, gb1b,
            qwb, qb0b, nullptr, Wacc, msum[t & 1]);
        rowgemmG_kernel<<<dim3(CBS, 3*CD/128, 2), dim3(128), 0, stream>>>(
            Wacc, Pg, bgv, giRaw, slots, gru_whh, gru_bhh, ghRaw, msum[t & 1], 3 * CD, CD);
        gate_mlp1_kernel<<<dim3(CBS, 8), dim3(128), 0, stream>>>(giRaw, ghRaw, slots,
            mlp_ln_g, mlp_ln_b, mlp_w1, mlp_b1, mlp_w2, snewb, slotsAcc,
            Wacc, msum[(t + 1) & 1]);
        slotsup_kernel<<<CBS, blk, 0, stream>>>(slotsAcc, mlp_b2, snewb,
            ln_g, ln_b, wqbb, Pq, slots, qwb, qb0b);
    }
    // final: write attn (+ msum for its m0), then fused scale + out GEMV
    dotsv_kernel<<<gridBN, blk, 0, stream>>>(KVX, S_pB, S_sB,
        msum[0], 1, G2b, gb1b, qwb, qb0b, attnb, nullptr, msum[1]);
    final_kernel<<<dim3(CBS, 3), dim3(128), 0, stream>>>(slots, fin_w, fin_b,
        out0, attnb, msum[1]);
}